// Round 10
// baseline (278.301 us; speedup 1.0000x reference)
//
#include <hip/hip_runtime.h>
#include <math.h>

// Problem constants (fixed by reference): B=64, N=512, D=64, H=4, C=64, L=3
// Workspace layout (floats), ws >= 256 MB:
//   xbuf [0 .. 2097152)         : layer activations x (8 MB)
//   hT   [2097152 .. 10485760)  : h TRANSPOSED [head][c][b*512+n] (32 MB)
//   meta [10485760 .. 11534336) : prep metadata (4 MB)
// History: R23 = 237.2 BEST (fused linprep grid 256x256thr, wave-indep lin).
// Mega arc DEAD. agg knobs (R20 coalesce / R21 syncs / R25 TLP) all
// neutral -> agg abandoned at ~26us, reverted to R21 2-ch here.
// R22 counters: linprep at 1 wave/SIMD -> VALUBusy 13% = latency-exposed.
// R24 lesson: never shrink grid below 256 CUs.
// R26 (this): linprep at 1024 threads (16 waves = 4 waves/SIMD), grid 256:
//   - lin: wave wq owns tiles wq, wq+16 (2 each, 1-deep prefetch); W-frags
//     re-read from LDS per tile (R24's bit-identical body) -> VGPR <= 128
//   - prep: executed REDUNDANTLY by all 4 thread-quarters on t255=t&255
//     (identical deterministic data -> same-value benign races; global
//     stores gated t<256). Sort network untouched -> bit-identical.
// Decision rule: >=237 -> revert to exact R23; ~237 is the structural floor.

using short8  = __attribute__((ext_vector_type(8))) short;
using floatx4 = __attribute__((ext_vector_type(4))) float;

__device__ inline unsigned short f2bf(float f) {
    union { float f; unsigned u; } v; v.f = f;
    unsigned u = v.u + 0x7FFFu + ((v.u >> 16) & 1u);   // round-to-nearest-even
    return (unsigned short)(u >> 16);
}
__device__ inline float bf2f(unsigned short s) {
    union { float f; unsigned u; } v; v.u = ((unsigned)s) << 16;
    return v.f;
}

// 8 floats (two float4) -> split-bf16 hi/lo short8 fragments, in registers.
__device__ inline void cvt8(const float4 a, const float4 b, short8& hi, short8& lo) {
    float f[8] = {a.x, a.y, a.z, a.w, b.x, b.y, b.z, b.w};
    short8 H, L;
#pragma unroll
    for (int i = 0; i < 8; ++i) {
        unsigned short h = f2bf(f[i]);
        H[i] = (short)h;
        L[i] = (short)f2bf(f[i] - bf2f(h));
    }
    hi = H; lo = L;
}

// ---------------------------------------------------------------------------
// Kernel A+B1 fused: linprep v3 (R26) — 1024 threads, 4 waves/SIMD.
// grid 256 = (b,head).
// ---------------------------------------------------------------------------
__global__ __launch_bounds__(1024) void linprep_kernel(const float* __restrict__ x,
                                                       const float* __restrict__ W,
                                                       const float* __restrict__ att_src,
                                                       const float* __restrict__ att_dst,
                                                       float* __restrict__ hT,
                                                       int* __restrict__ g_rank,
                                                       float* __restrict__ g_E1,
                                                       float* __restrict__ g_E2,
                                                       float* __restrict__ g_aZ,
                                                       float* __restrict__ g_bZ,
                                                       int* __restrict__ g_k) {
    __shared__ unsigned short WH[64 * 72], WL[64 * 72];
    __shared__ float sA[512], dA[512];      // s/d dots (then sA sorted in place)
    __shared__ int   s_idxE[512];
    __shared__ float z1suf[513], z2pre[513];
    __shared__ float wred[8];

    const int t  = threadIdx.x;
    const int bh = blockIdx.x;            // b*4 + head (matches meta layout)
    const int b  = bh >> 2;
    const int ct = bh & 3;                // head
    const int c0 = ct * 64;

    // ---- W staging + convert, ONCE per block (1024 thr: one float4 each) ----
    {
        int wrow = t >> 4, d4 = t & 15;
        float4 v = *(const float4*)(W + (size_t)(c0 + wrow) * 64 + d4 * 4);
        unsigned short h0 = f2bf(v.x), h1 = f2bf(v.y), h2 = f2bf(v.z), h3 = f2bf(v.w);
        ushort4 hi = make_ushort4(h0, h1, h2, h3);
        ushort4 lo = make_ushort4(f2bf(v.x - bf2f(h0)), f2bf(v.y - bf2f(h1)),
                                  f2bf(v.z - bf2f(h2)), f2bf(v.w - bf2f(h3)));
        *(ushort4*)&WH[wrow * 72 + d4 * 4] = hi;
        *(ushort4*)&WL[wrow * 72 + d4 * 4] = lo;
    }
    __syncthreads();

    const int lane = t & 63;
    const int wq   = t >> 6;              // wave 0..15
    const int mrow = lane & 15, quad = lane >> 4;

    float as_g[4], ad_g[4];
#pragma unroll
    for (int g = 0; g < 4; ++g) {
        as_g[g] = att_src[c0 + g * 16 + mrow];
        ad_g[g] = att_dst[c0 + g * 16 + mrow];
    }

    // ---- lin: wave wq owns tiles wq and wq+16 (frags from LDS per tile) ----
    const float* xbase = x + (size_t)(b * 512 + mrow) * 64 + quad * 8;
    float4 nxa = *(const float4*)(xbase + (size_t)wq * 1024);
    float4 nxb = *(const float4*)(xbase + (size_t)wq * 1024 + 4);
    float4 nxc = *(const float4*)(xbase + (size_t)wq * 1024 + 32);
    float4 nxd = *(const float4*)(xbase + (size_t)wq * 1024 + 36);

#pragma unroll 1
    for (int tl = wq; tl < 32; tl += 16) {
        float4 xa = nxa, xb = nxb, xc = nxc, xd = nxd;
        if (tl + 16 < 32) {
            const float* nb = xbase + (size_t)(tl + 16) * 1024;
            nxa = *(const float4*)(nb);
            nxb = *(const float4*)(nb + 4);
            nxc = *(const float4*)(nb + 32);
            nxd = *(const float4*)(nb + 36);
        }
        short8 ah0, al0, ah1, al1;
        cvt8(xa, xb, ah0, al0);
        cvt8(xc, xd, ah1, al1);

        floatx4 acc[4];
#pragma unroll
        for (int g = 0; g < 4; ++g) {
            const int wr = (g * 16 + mrow) * 72;
            short8 bh0 = *(const short8*)&WH[wr + quad * 8];
            short8 bh1 = *(const short8*)&WH[wr + 32 + quad * 8];
            short8 bl0 = *(const short8*)&WL[wr + quad * 8];
            short8 bl1 = *(const short8*)&WL[wr + 32 + quad * 8];
            floatx4 a = {0.f, 0.f, 0.f, 0.f};
            a = __builtin_amdgcn_mfma_f32_16x16x32_bf16(ah0, bh0, a, 0, 0, 0);
            a = __builtin_amdgcn_mfma_f32_16x16x32_bf16(ah1, bh1, a, 0, 0, 0);
            a = __builtin_amdgcn_mfma_f32_16x16x32_bf16(ah0, bl0, a, 0, 0, 0);
            a = __builtin_amdgcn_mfma_f32_16x16x32_bf16(ah1, bl1, a, 0, 0, 0);
            a = __builtin_amdgcn_mfma_f32_16x16x32_bf16(al0, bh0, a, 0, 0, 0);
            a = __builtin_amdgcn_mfma_f32_16x16x32_bf16(al1, bh1, a, 0, 0, 0);
            acc[g] = a;
        }

        const int r0 = b * 512 + tl * 16;
#pragma unroll
        for (int g = 0; g < 4; ++g) {
            *(float4*)&hT[(size_t)(ct * 64 + g * 16 + mrow) * 32768 + r0 + quad * 4] =
                make_float4(acc[g][0], acc[g][1], acc[g][2], acc[g][3]);
        }

        float ps[4], pd[4];
#pragma unroll
        for (int reg = 0; reg < 4; ++reg) {
            ps[reg] = acc[0][reg] * as_g[0] + acc[1][reg] * as_g[1]
                    + acc[2][reg] * as_g[2] + acc[3][reg] * as_g[3];
            pd[reg] = acc[0][reg] * ad_g[0] + acc[1][reg] * ad_g[1]
                    + acc[2][reg] * ad_g[2] + acc[3][reg] * ad_g[3];
        }
#pragma unroll
        for (int m = 1; m <= 8; m <<= 1) {
#pragma unroll
            for (int reg = 0; reg < 4; ++reg) {
                ps[reg] += __shfl_xor(ps[reg], m, 64);
                pd[reg] += __shfl_xor(pd[reg], m, 64);
            }
        }
        if (mrow < 4) {
            sA[tl * 16 + quad * 4 + mrow] = ps[mrow];
            dA[tl * 16 + quad * 4 + mrow] = pd[mrow];
        }
    }
    __syncthreads();

    // ===== prep body: REDUNDANT execution on t255 = t & 255 (bit-identical;
    // all cross-quarter races are same-address-same-value). Global stores
    // gated on t < 256. =====
    const int t255 = t & 255;
    const int wid4 = (t >> 6) & 3;

    float dreg[2];
    for (int rr = 0; rr < 2; ++rr) dreg[rr] = dA[t255 + rr * 256];

    float v0 = sA[2 * t255], v1 = sA[2 * t255 + 1];
    int id0 = 2 * t255, id1 = 2 * t255 + 1;
    for (int k = 2; k <= 512; k <<= 1) {
        for (int j = k >> 1; j >= 1; j >>= 1) {
            bool asc = ((t255 & (k >> 1)) == 0);
            if (j == 1) {
                bool sw = asc ? (v0 > v1) : (v0 < v1);
                if (sw) { float tv = v0; v0 = v1; v1 = tv; int ti = id0; id0 = id1; id1 = ti; }
            } else if (j <= 64) {
                int m = j >> 1;
                float w0 = __shfl_xor(v0, m, 64);
                int  wi0 = __shfl_xor(id0, m, 64);
                float w1 = __shfl_xor(v1, m, 64);
                int  wi1 = __shfl_xor(id1, m, 64);
                bool low = ((t255 & m) == 0);
                bool wantmin = (low == asc);
                if (wantmin ? (w0 < v0) : (w0 > v0)) { v0 = w0; id0 = wi0; }
                if (wantmin ? (w1 < v1) : (w1 > v1)) { v1 = w1; id1 = wi1; }
            } else {
                int m = j >> 1;
                sA[2 * t255] = v0; sA[2 * t255 + 1] = v1;
                s_idxE[2 * t255] = id0; s_idxE[2 * t255 + 1] = id1;
                __syncthreads();
                int tp = t255 ^ m;
                float w0 = sA[2 * tp], w1 = sA[2 * tp + 1];
                int wi0 = s_idxE[2 * tp], wi1 = s_idxE[2 * tp + 1];
                bool low = ((t255 & m) == 0);
                bool wantmin = (low == asc);
                if (wantmin ? (w0 < v0) : (w0 > v0)) { v0 = w0; id0 = wi0; }
                if (wantmin ? (w1 < v1) : (w1 > v1)) { v1 = w1; id1 = wi1; }
                __syncthreads();
            }
        }
    }

    sA[2 * t255] = v0; sA[2 * t255 + 1] = v1;
    __syncthreads();
    const float M = sA[511];
    float e1_0 = __expf(v0 - M), e1_1 = __expf(v1 - M);
    float e2_0 = __expf(0.2f * (v0 - M)), e2_1 = __expf(0.2f * (v1 - M));
    if (t < 256) {   // scatter by original id (permutation -> race-free)
        const int base = bh * 512;
        g_E1[base + id0] = e1_0;  g_E1[base + id1] = e1_1;
        g_E2[base + id0] = e2_0;  g_E2[base + id1] = e2_1;
        g_rank[base + id0] = 2 * t255;  g_rank[base + id1] = 2 * t255 + 1;
    }

    float S1 = e1_0 + e1_1, S2 = e2_0 + e2_1;
    float i1 = S1, i2 = S2;
    for (int off = 1; off < 64; off <<= 1) {
        float u1 = __shfl_up(i1, off, 64);
        float u2 = __shfl_up(i2, off, 64);
        if (lane >= off) { i1 += u1; i2 += u2; }
    }
    if (lane == 63) { wred[wid4] = i1; wred[4 + wid4] = i2; }
    __syncthreads();
    float off1 = 0.f, off2 = 0.f;
    for (int w = 0; w < wid4; ++w) { off1 += wred[w]; off2 += wred[4 + w]; }
    const float T1 = wred[0] + wred[1] + wred[2] + wred[3];
    const float T2 = wred[4] + wred[5] + wred[6] + wred[7];
    float pre1 = off1 + i1 - S1;
    float pre2 = off2 + i2 - S2;
    z1suf[2 * t255] = T1 - pre1;
    z1suf[2 * t255 + 1] = T1 - pre1 - e1_0;
    z2pre[2 * t255] = pre2;
    z2pre[2 * t255 + 1] = pre2 + e2_0;
    if (t255 == 0) { z1suf[512] = 0.f; z2pre[512] = T2; }
    __syncthreads();

    if (t < 256) {
        for (int rr = 0; rr < 2; ++rr) {
            int i = t255 + rr * 256;
            float d = dreg[rr];
            int lo = 0, hi = 512;
            while (lo < hi) {
                int mid = (lo + hi) >> 1;
                if (d + sA[mid] >= 0.f) hi = mid; else lo = mid + 1;
            }
            int k = lo;
            float g = d + M;
            float G = (g >= 0.f) ? g : 0.2f * g;
            float al = __expf(g - G);
            float be = __expf(0.2f * g - G);
            float Z = al * z1suf[k] + be * z2pre[k];
            float inv = 1.0f / Z;
            g_aZ[bh * 512 + i] = al * inv;
            g_bZ[bh * 512 + i] = be * inv;
            g_k[bh * 512 + i]  = k;
        }
    }
}

// ---------------------------------------------------------------------------
// Kernel B2: attn_agg_fin v7 (R21/R23 2-ch version, REVERTED per rule).
// grid = 64 b x 32 cg = 2048 blocks, 256 thr (4 waves = 4 heads).
// ---------------------------------------------------------------------------
__global__ __launch_bounds__(256) void attn_agg_fin(const float* __restrict__ hT,
                                                    const int* __restrict__ g_rank,
                                                    const float* __restrict__ g_E1,
                                                    const float* __restrict__ g_E2,
                                                    const float* __restrict__ g_aZ,
                                                    const float* __restrict__ g_bZ,
                                                    const int* __restrict__ g_k,
                                                    const float* __restrict__ bias,
                                                    float* __restrict__ x) {
    const int b  = blockIdx.x & 63;
    const int cg = blockIdx.x >> 6;        // 0..31
    const int c0 = cg * 2;
    const int t = threadIdx.x;
    const int lane = t & 63, wv = t >> 6;  // wv = head 0..3

    __shared__ float A1[4][2][512], A2[4][2][512];
    __shared__ float tots[4][2];

    {
        const int bh = b * 4 + wv;
        const int base = bh * 512;
        const float* hTb = hT + (size_t)(wv * 64 + c0) * 32768 + (size_t)b * 512;
#pragma unroll
        for (int it = 0; it < 8; ++it) {
            int j = it * 64 + lane;
            int rk = g_rank[base + j];
            float e1 = g_E1[base + j];
            float e2 = g_E2[base + j];
            float h0 = hTb[j];
            float h1 = hTb[32768 + j];
            int pk = ((rk & 7) << 6) | (rk >> 3);
            A1[wv][0][pk] = e1 * h0;  A2[wv][0][pk] = e2 * h0;
            A1[wv][1][pk] = e1 * h1;  A2[wv][1][pk] = e2 * h1;
        }
#pragma unroll
        for (int cc = 0; cc < 2; ++cc) {
            float v1[8], v2[8];
#pragma unroll
            for (int i = 0; i < 8; ++i) {
                v1[i] = A1[wv][cc][i * 64 + lane];
                v2[i] = A2[wv][cc][i * 64 + lane];
            }
            float s1 = 0.f, s2 = 0.f;
#pragma unroll
            for (int i = 0; i < 8; ++i) { s1 += v1[i]; s2 += v2[i]; }
            float suf = s1;
#pragma unroll
            for (int off = 1; off < 64; off <<= 1) {
                float u = __shfl_down(suf, off, 64);
                if (lane + off < 64) suf += u;
            }
            float run = suf - s1;
            float pre = s2;
#pragma unroll
            for (int off = 1; off < 64; off <<= 1) {
                float u = __shfl_up(pre, off, 64);
                if (lane >= off) pre += u;
            }
            float run2 = pre - s2;
            if (lane == 63) tots[wv][cc] = pre;
#pragma unroll
            for (int i = 7; i >= 0; --i) { run += v1[i]; v1[i] = run; }
#pragma unroll
            for (int i = 0; i < 8; ++i) { float tv = v2[i]; v2[i] = run2; run2 += tv; }
#pragma unroll
            for (int i = 0; i < 8; ++i) {
                A1[wv][cc][i * 64 + lane] = v1[i];
                A2[wv][cc][i * 64 + lane] = v2[i];
            }
        }
    }
    __syncthreads();

    const float bv0 = bias[c0], bv1 = bias[c0 + 1];
#pragma unroll
    for (int rr = 0; rr < 2; ++rr) {
        const int i = t + rr * 256;
        float a0 = 0.f, a1 = 0.f;
#pragma unroll
        for (int head = 0; head < 4; ++head) {
            const int base = (b * 4 + head) * 512;
            float aZ = g_aZ[base + i];
            float bZ = g_bZ[base + i];
            int k = g_k[base + i];
            if (k < 512) {
                int pk = ((k & 7) << 6) | (k >> 3);
                a0 += aZ * A1[head][0][pk] + bZ * A2[head][0][pk];
                a1 += aZ * A1[head][1][pk] + bZ * A2[head][1][pk];
            } else {
                a0 += bZ * tots[head][0];
                a1 += bZ * tots[head][1];
            }
        }
        float2 o = make_float2(fmaxf(0.25f * a0 + bv0, 0.f),
                               fmaxf(0.25f * a1 + bv1, 0.f));
        *(float2*)&x[(size_t)(b * 512 + i) * 64 + c0] = o;
    }
}

// ---------------------------------------------------------------------------
// Kernel D: readout (unchanged)
// ---------------------------------------------------------------------------
__global__ __launch_bounds__(256) void readout_kernel(const float* __restrict__ x,
                                                      const float* __restrict__ rw,
                                                      const float* __restrict__ rb,
                                                      float* __restrict__ out) {
    __shared__ float red[4][64];
    __shared__ float pooled[64];
    int b = blockIdx.x, t = threadIdx.x;
    int c = t & 63, q = t >> 6;
    float acc = 0.f;
    for (int n = q; n < 512; n += 4) acc += x[((size_t)b * 512 + n) * 64 + c];
    red[q][c] = acc;
    __syncthreads();
    if (t < 64) pooled[t] = (red[0][t] + red[1][t] + red[2][t] + red[3][t]) * (1.0f / 512.0f);
    __syncthreads();
    if (t < 64) {
        float a = rb[t];
        for (int cc = 0; cc < 64; ++cc) a += pooled[cc] * rw[t * 64 + cc];
        out[b * 64 + t] = a;
    }
}

extern "C" void kernel_launch(void* const* d_in, const int* in_sizes, int n_in,
                              void* d_out, int out_size, void* d_ws, size_t ws_size,
                              hipStream_t stream) {
    const float* emb       = (const float*)d_in[0];
    const float* lin_w     = (const float*)d_in[1];
    const float* att_src   = (const float*)d_in[2];
    const float* att_dst   = (const float*)d_in[3];
    const float* conv_b    = (const float*)d_in[4];
    const float* readout_w = (const float*)d_in[5];
    const float* readout_b = (const float*)d_in[6];
    float* out = (float*)d_out;

    float* ws   = (float*)d_ws;
    float* xbuf = ws;                    // 8 MB
    float* hT   = ws + 2097152;          // 32 MB, [head][c][b*512+n]
    float* meta = ws + 10485760;         // 4 MB

    int*   g_rank = (int*)meta;          // inverse rank (by original id)
    float* g_E1   = meta + 131072;       // indexed by ORIGINAL id
    float* g_E2   = meta + 262144;       // indexed by ORIGINAL id
    float* g_aZ   = meta + 393216;
    float* g_bZ   = meta + 524288;
    int*   g_k    = (int*)(meta + 655360);

    for (int l = 0; l < 3; ++l) {
        const float* xin = (l == 0) ? emb : xbuf;
        linprep_kernel<<<256, 1024, 0, stream>>>(xin, lin_w + (size_t)l * 16384,
                                                 att_src + l * 256, att_dst + l * 256,
                                                 hT, g_rank, g_E1, g_E2, g_aZ, g_bZ, g_k);
        attn_agg_fin<<<2048, 256, 0, stream>>>(hT, g_rank, g_E1, g_E2, g_aZ, g_bZ, g_k,
                                               conv_b + l * 64, xbuf);
    }
    readout_kernel<<<64, 256, 0, stream>>>(xbuf, readout_w, readout_b, out);
}

// Round 11
// 235.944 us; speedup vs baseline: 1.1795x; 1.1795x over previous
//
#include <hip/hip_runtime.h>
#include <math.h>

// Problem constants (fixed by reference): B=64, N=512, D=64, H=4, C=64, L=3
// Workspace layout (floats), ws >= 256 MB:
//   xbuf [0 .. 2097152)         : layer activations x (8 MB)
//   hT   [2097152 .. 10485760)  : h TRANSPOSED [head][c][b*512+n] (32 MB)
//   meta [10485760 .. 11534336) : prep metadata (4 MB)
// History: R23 = 237.2 BEST (fused linprep grid 256x256thr, wave-indep lin,
// agg v7 2-ch). Mega arc DEAD. agg knobs (R20/R21/R25) neutral. Occupancy
// ledger complete: R15 266 / R23 237 / R24 532 / R26 278 -> R23's config is
// the measured optimum (R26: redundant sort x4 on same SIMDs + 16-wave
// syncs + LDS frag re-reads ate the occupancy gain).
// R27 (this): EXACT R23 revert + ONE zero-risk tweak: agg blockIdx swizzle
// grouping all 32 cg-blocks of a given b on XCD b%8 (id%8 == b%8). The 32
// blocks share the SAME 48KB of meta (rank/E1/E2/aZ/bZ/k x 4 heads) -> 32x
// reuse lands in one XCD L2 instead of being re-fetched by 8. Bijective
// remap, bit-identical output.
// Decision rule: >=237.2 -> swizzle refuted; declare ~237 the floor.

using short8  = __attribute__((ext_vector_type(8))) short;
using floatx4 = __attribute__((ext_vector_type(4))) float;

__device__ inline unsigned short f2bf(float f) {
    union { float f; unsigned u; } v; v.f = f;
    unsigned u = v.u + 0x7FFFu + ((v.u >> 16) & 1u);   // round-to-nearest-even
    return (unsigned short)(u >> 16);
}
__device__ inline float bf2f(unsigned short s) {
    union { float f; unsigned u; } v; v.u = ((unsigned)s) << 16;
    return v.f;
}

// 8 floats (two float4) -> split-bf16 hi/lo short8 fragments, in registers.
__device__ inline void cvt8(const float4 a, const float4 b, short8& hi, short8& lo) {
    float f[8] = {a.x, a.y, a.z, a.w, b.x, b.y, b.z, b.w};
    short8 H, L;
#pragma unroll
    for (int i = 0; i < 8; ++i) {
        unsigned short h = f2bf(f[i]);
        H[i] = (short)h;
        L[i] = (short)f2bf(f[i] - bf2f(h));
    }
    hi = H; lo = L;
}

// ---------------------------------------------------------------------------
// Kernel A+B1 fused: linprep v2 (R23, UNCHANGED) — wave-independent lin +
// verbatim prep. grid 256 = (b,head), 256 threads.
// ---------------------------------------------------------------------------
__global__ __launch_bounds__(256) void linprep_kernel(const float* __restrict__ x,
                                                      const float* __restrict__ W,
                                                      const float* __restrict__ att_src,
                                                      const float* __restrict__ att_dst,
                                                      float* __restrict__ hT,
                                                      int* __restrict__ g_rank,
                                                      float* __restrict__ g_E1,
                                                      float* __restrict__ g_E2,
                                                      float* __restrict__ g_aZ,
                                                      float* __restrict__ g_bZ,
                                                      int* __restrict__ g_k) {
    __shared__ unsigned short WH[64 * 72], WL[64 * 72];
    __shared__ float sA[512], dA[512];      // s/d dots (then sA sorted in place)
    __shared__ int   s_idxE[512];
    __shared__ float z1suf[513], z2pre[513];
    __shared__ float wred[8];

    const int t  = threadIdx.x;
    const int bh = blockIdx.x;            // b*4 + head (matches meta layout)
    const int b  = bh >> 2;
    const int ct = bh & 3;                // head
    const int c0 = ct * 64;

    // ---- W staging + convert, ONCE per block ----
#pragma unroll
    for (int q = 0; q < 4; ++q) {
        int f = q * 256 + t;
        int wrow = f >> 4, d4 = f & 15;
        float4 v = *(const float4*)(W + (size_t)(c0 + wrow) * 64 + d4 * 4);
        unsigned short h0 = f2bf(v.x), h1 = f2bf(v.y), h2 = f2bf(v.z), h3 = f2bf(v.w);
        ushort4 hi = make_ushort4(h0, h1, h2, h3);
        ushort4 lo = make_ushort4(f2bf(v.x - bf2f(h0)), f2bf(v.y - bf2f(h1)),
                                  f2bf(v.z - bf2f(h2)), f2bf(v.w - bf2f(h3)));
        *(ushort4*)&WH[wrow * 72 + d4 * 4] = hi;
        *(ushort4*)&WL[wrow * 72 + d4 * 4] = lo;
    }
    __syncthreads();

    const int lane = t & 63, wv = t >> 6;
    const int mrow = lane & 15, quad = lane >> 4;

    // ---- per-wave W fragments for ALL 4 channel groups ----
    short8 bhf[4][2], blf[4][2];
#pragma unroll
    for (int g = 0; g < 4; ++g)
#pragma unroll
        for (int kk = 0; kk < 2; ++kk) {
            int ko = kk * 32 + quad * 8;
            bhf[g][kk] = *(const short8*)&WH[(g * 16 + mrow) * 72 + ko];
            blf[g][kk] = *(const short8*)&WL[(g * 16 + mrow) * 72 + ko];
        }
    float as_g[4], ad_g[4];
#pragma unroll
    for (int g = 0; g < 4; ++g) {
        as_g[g] = att_src[c0 + g * 16 + mrow];
        ad_g[g] = att_dst[c0 + g * 16 + mrow];
    }

    // ---- wave-independent tile loop: wave wv owns tiles wv, wv+4, ..., wv+28
    const float* xbase = x + (size_t)(b * 512 + mrow) * 64 + quad * 8;
    float4 nxa = *(const float4*)(xbase + (size_t)wv * 1024);
    float4 nxb = *(const float4*)(xbase + (size_t)wv * 1024 + 4);
    float4 nxc = *(const float4*)(xbase + (size_t)wv * 1024 + 32);
    float4 nxd = *(const float4*)(xbase + (size_t)wv * 1024 + 36);

#pragma unroll 1
    for (int tl = wv; tl < 32; tl += 4) {
        float4 xa = nxa, xb = nxb, xc = nxc, xd = nxd;
        if (tl + 4 < 32) {
            const float* nb = xbase + (size_t)(tl + 4) * 1024;
            nxa = *(const float4*)(nb);
            nxb = *(const float4*)(nb + 4);
            nxc = *(const float4*)(nb + 32);
            nxd = *(const float4*)(nb + 36);
        }
        short8 ah0, al0, ah1, al1;
        cvt8(xa, xb, ah0, al0);
        cvt8(xc, xd, ah1, al1);

        floatx4 acc[4];
#pragma unroll
        for (int g = 0; g < 4; ++g) {
            floatx4 a = {0.f, 0.f, 0.f, 0.f};
            a = __builtin_amdgcn_mfma_f32_16x16x32_bf16(ah0, bhf[g][0], a, 0, 0, 0);
            a = __builtin_amdgcn_mfma_f32_16x16x32_bf16(ah1, bhf[g][1], a, 0, 0, 0);
            a = __builtin_amdgcn_mfma_f32_16x16x32_bf16(ah0, blf[g][0], a, 0, 0, 0);
            a = __builtin_amdgcn_mfma_f32_16x16x32_bf16(ah1, blf[g][1], a, 0, 0, 0);
            a = __builtin_amdgcn_mfma_f32_16x16x32_bf16(al0, bhf[g][0], a, 0, 0, 0);
            a = __builtin_amdgcn_mfma_f32_16x16x32_bf16(al1, bhf[g][1], a, 0, 0, 0);
            acc[g] = a;
        }

        const int r0 = b * 512 + tl * 16;
#pragma unroll
        for (int g = 0; g < 4; ++g) {
            *(float4*)&hT[(size_t)(ct * 64 + g * 16 + mrow) * 32768 + r0 + quad * 4] =
                make_float4(acc[g][0], acc[g][1], acc[g][2], acc[g][3]);
        }

        float ps[4], pd[4];
#pragma unroll
        for (int reg = 0; reg < 4; ++reg) {
            ps[reg] = acc[0][reg] * as_g[0] + acc[1][reg] * as_g[1]
                    + acc[2][reg] * as_g[2] + acc[3][reg] * as_g[3];
            pd[reg] = acc[0][reg] * ad_g[0] + acc[1][reg] * ad_g[1]
                    + acc[2][reg] * ad_g[2] + acc[3][reg] * ad_g[3];
        }
#pragma unroll
        for (int m = 1; m <= 8; m <<= 1) {
#pragma unroll
            for (int reg = 0; reg < 4; ++reg) {
                ps[reg] += __shfl_xor(ps[reg], m, 64);
                pd[reg] += __shfl_xor(pd[reg], m, 64);
            }
        }
        if (mrow < 4) {
            sA[tl * 16 + quad * 4 + mrow] = ps[mrow];
            dA[tl * 16 + quad * 4 + mrow] = pd[mrow];
        }
    }
    __syncthreads();

    // ======================= prep body (verbatim) ==========================
    const int wid = t >> 6;

    float dreg[2];
    for (int rr = 0; rr < 2; ++rr) dreg[rr] = dA[t + rr * 256];

    float v0 = sA[2 * t], v1 = sA[2 * t + 1];
    int id0 = 2 * t, id1 = 2 * t + 1;
    for (int k = 2; k <= 512; k <<= 1) {
        for (int j = k >> 1; j >= 1; j >>= 1) {
            bool asc = ((t & (k >> 1)) == 0);
            if (j == 1) {
                bool sw = asc ? (v0 > v1) : (v0 < v1);
                if (sw) { float tv = v0; v0 = v1; v1 = tv; int ti = id0; id0 = id1; id1 = ti; }
            } else if (j <= 64) {
                int m = j >> 1;
                float w0 = __shfl_xor(v0, m, 64);
                int  wi0 = __shfl_xor(id0, m, 64);
                float w1 = __shfl_xor(v1, m, 64);
                int  wi1 = __shfl_xor(id1, m, 64);
                bool low = ((t & m) == 0);
                bool wantmin = (low == asc);
                if (wantmin ? (w0 < v0) : (w0 > v0)) { v0 = w0; id0 = wi0; }
                if (wantmin ? (w1 < v1) : (w1 > v1)) { v1 = w1; id1 = wi1; }
            } else {
                int m = j >> 1;
                sA[2 * t] = v0; sA[2 * t + 1] = v1;
                s_idxE[2 * t] = id0; s_idxE[2 * t + 1] = id1;
                __syncthreads();
                int tp = t ^ m;
                float w0 = sA[2 * tp], w1 = sA[2 * tp + 1];
                int wi0 = s_idxE[2 * tp], wi1 = s_idxE[2 * tp + 1];
                bool low = ((t & m) == 0);
                bool wantmin = (low == asc);
                if (wantmin ? (w0 < v0) : (w0 > v0)) { v0 = w0; id0 = wi0; }
                if (wantmin ? (w1 < v1) : (w1 > v1)) { v1 = w1; id1 = wi1; }
                __syncthreads();
            }
        }
    }

    sA[2 * t] = v0; sA[2 * t + 1] = v1;
    __syncthreads();
    const float M = sA[511];
    float e1_0 = __expf(v0 - M), e1_1 = __expf(v1 - M);
    float e2_0 = __expf(0.2f * (v0 - M)), e2_1 = __expf(0.2f * (v1 - M));
    {
        const int base = bh * 512;
        g_E1[base + id0] = e1_0;  g_E1[base + id1] = e1_1;
        g_E2[base + id0] = e2_0;  g_E2[base + id1] = e2_1;
        g_rank[base + id0] = 2 * t;  g_rank[base + id1] = 2 * t + 1;
    }

    float S1 = e1_0 + e1_1, S2 = e2_0 + e2_1;
    float i1 = S1, i2 = S2;
    for (int off = 1; off < 64; off <<= 1) {
        float u1 = __shfl_up(i1, off, 64);
        float u2 = __shfl_up(i2, off, 64);
        if (lane >= off) { i1 += u1; i2 += u2; }
    }
    if (lane == 63) { wred[wid] = i1; wred[4 + wid] = i2; }
    __syncthreads();
    float off1 = 0.f, off2 = 0.f;
    for (int w = 0; w < wid; ++w) { off1 += wred[w]; off2 += wred[4 + w]; }
    const float T1 = wred[0] + wred[1] + wred[2] + wred[3];
    const float T2 = wred[4] + wred[5] + wred[6] + wred[7];
    float pre1 = off1 + i1 - S1;
    float pre2 = off2 + i2 - S2;
    z1suf[2 * t] = T1 - pre1;
    z1suf[2 * t + 1] = T1 - pre1 - e1_0;
    z2pre[2 * t] = pre2;
    z2pre[2 * t + 1] = pre2 + e2_0;
    if (t == 0) { z1suf[512] = 0.f; z2pre[512] = T2; }
    __syncthreads();

    for (int rr = 0; rr < 2; ++rr) {
        int i = t + rr * 256;
        float d = dreg[rr];
        int lo = 0, hi = 512;
        while (lo < hi) {
            int mid = (lo + hi) >> 1;
            if (d + sA[mid] >= 0.f) hi = mid; else lo = mid + 1;
        }
        int k = lo;
        float g = d + M;
        float G = (g >= 0.f) ? g : 0.2f * g;
        float al = __expf(g - G);
        float be = __expf(0.2f * g - G);
        float Z = al * z1suf[k] + be * z2pre[k];
        float inv = 1.0f / Z;
        g_aZ[bh * 512 + i] = al * inv;
        g_bZ[bh * 512 + i] = be * inv;
        g_k[bh * 512 + i]  = k;
    }
}

// ---------------------------------------------------------------------------
// Kernel B2: attn_agg_fin v7 (R23 body) + R27 XCD swizzle: all 32 cg-blocks
// of a given b land on XCD b%8 (blockIdx%8 == b%8) -> the 48KB of meta they
// share is fetched into ONE XCD L2 instead of 8.
// grid = 2048 blocks, 256 thr (4 waves = 4 heads).
// ---------------------------------------------------------------------------
__global__ __launch_bounds__(256) void attn_agg_fin(const float* __restrict__ hT,
                                                    const int* __restrict__ g_rank,
                                                    const float* __restrict__ g_E1,
                                                    const float* __restrict__ g_E2,
                                                    const float* __restrict__ g_aZ,
                                                    const float* __restrict__ g_bZ,
                                                    const int* __restrict__ g_k,
                                                    const float* __restrict__ bias,
                                                    float* __restrict__ x) {
    // R27 bijective swizzle: id%8 = b%8.
    const int r8 = blockIdx.x & 7;
    const int qq = blockIdx.x >> 3;
    const int cg = qq & 31;                // 0..31
    const int b  = ((qq >> 5) << 3) | r8;  // 0..63
    const int c0 = cg * 2;
    const int t = threadIdx.x;
    const int lane = t & 63, wv = t >> 6;  // wv = head 0..3

    __shared__ float A1[4][2][512], A2[4][2][512];
    __shared__ float tots[4][2];

    {
        const int bh = b * 4 + wv;
        const int base = bh * 512;
        const float* hTb = hT + (size_t)(wv * 64 + c0) * 32768 + (size_t)b * 512;
#pragma unroll
        for (int it = 0; it < 8; ++it) {
            int j = it * 64 + lane;
            int rk = g_rank[base + j];
            float e1 = g_E1[base + j];
            float e2 = g_E2[base + j];
            float h0 = hTb[j];
            float h1 = hTb[32768 + j];
            int pk = ((rk & 7) << 6) | (rk >> 3);
            A1[wv][0][pk] = e1 * h0;  A2[wv][0][pk] = e2 * h0;
            A1[wv][1][pk] = e1 * h1;  A2[wv][1][pk] = e2 * h1;
        }
#pragma unroll
        for (int cc = 0; cc < 2; ++cc) {
            float v1[8], v2[8];
#pragma unroll
            for (int i = 0; i < 8; ++i) {
                v1[i] = A1[wv][cc][i * 64 + lane];
                v2[i] = A2[wv][cc][i * 64 + lane];
            }
            float s1 = 0.f, s2 = 0.f;
#pragma unroll
            for (int i = 0; i < 8; ++i) { s1 += v1[i]; s2 += v2[i]; }
            float suf = s1;
#pragma unroll
            for (int off = 1; off < 64; off <<= 1) {
                float u = __shfl_down(suf, off, 64);
                if (lane + off < 64) suf += u;
            }
            float run = suf - s1;
            float pre = s2;
#pragma unroll
            for (int off = 1; off < 64; off <<= 1) {
                float u = __shfl_up(pre, off, 64);
                if (lane >= off) pre += u;
            }
            float run2 = pre - s2;
            if (lane == 63) tots[wv][cc] = pre;
#pragma unroll
            for (int i = 7; i >= 0; --i) { run += v1[i]; v1[i] = run; }
#pragma unroll
            for (int i = 0; i < 8; ++i) { float tv = v2[i]; v2[i] = run2; run2 += tv; }
#pragma unroll
            for (int i = 0; i < 8; ++i) {
                A1[wv][cc][i * 64 + lane] = v1[i];
                A2[wv][cc][i * 64 + lane] = v2[i];
            }
        }
    }
    __syncthreads();

    const float bv0 = bias[c0], bv1 = bias[c0 + 1];
#pragma unroll
    for (int rr = 0; rr < 2; ++rr) {
        const int i = t + rr * 256;
        float a0 = 0.f, a1 = 0.f;
#pragma unroll
        for (int head = 0; head < 4; ++head) {
            const int base = (b * 4 + head) * 512;
            float aZ = g_aZ[base + i];
            float bZ = g_bZ[base + i];
            int k = g_k[base + i];
            if (k < 512) {
                int pk = ((k & 7) << 6) | (k >> 3);
                a0 += aZ * A1[head][0][pk] + bZ * A2[head][0][pk];
                a1 += aZ * A1[head][1][pk] + bZ * A2[head][1][pk];
            } else {
                a0 += bZ * tots[head][0];
                a1 += bZ * tots[head][1];
            }
        }
        float2 o = make_float2(fmaxf(0.25f * a0 + bv0, 0.f),
                               fmaxf(0.25f * a1 + bv1, 0.f));
        *(float2*)&x[(size_t)(b * 512 + i) * 64 + c0] = o;
    }
}

// ---------------------------------------------------------------------------
// Kernel D: readout (unchanged)
// ---------------------------------------------------------------------------
__global__ __launch_bounds__(256) void readout_kernel(const float* __restrict__ x,
                                                      const float* __restrict__ rw,
                                                      const float* __restrict__ rb,
                                                      float* __restrict__ out) {
    __shared__ float red[4][64];
    __shared__ float pooled[64];
    int b = blockIdx.x, t = threadIdx.x;
    int c = t & 63, q = t >> 6;
    float acc = 0.f;
    for (int n = q; n < 512; n += 4) acc += x[((size_t)b * 512 + n) * 64 + c];
    red[q][c] = acc;
    __syncthreads();
    if (t < 64) pooled[t] = (red[0][t] + red[1][t] + red[2][t] + red[3][t]) * (1.0f / 512.0f);
    __syncthreads();
    if (t < 64) {
        float a = rb[t];
        for (int cc = 0; cc < 64; ++cc) a += pooled[cc] * rw[t * 64 + cc];
        out[b * 64 + t] = a;
    }
}

extern "C" void kernel_launch(void* const* d_in, const int* in_sizes, int n_in,
                              void* d_out, int out_size, void* d_ws, size_t ws_size,
                              hipStream_t stream) {
    const float* emb       = (const float*)d_in[0];
    const float* lin_w     = (const float*)d_in[1];
    const float* att_src   = (const float*)d_in[2];
    const float* att_dst   = (const float*)d_in[3];
    const float* conv_b    = (const float*)d_in[4];
    const float* readout_w = (const float*)d_in[5];
    const float* readout_b = (const float*)d_in[6];
    float* out = (float*)d_out;

    float* ws   = (float*)d_ws;
    float* xbuf = ws;                    // 8 MB
    float* hT   = ws + 2097152;          // 32 MB, [head][c][b*512+n]
    float* meta = ws + 10485760;         // 4 MB

    int*   g_rank = (int*)meta;          // inverse rank (by original id)
    float* g_E1   = meta + 131072;       // indexed by ORIGINAL id
    float* g_E2   = meta + 262144;       // indexed by ORIGINAL id
    float* g_aZ   = meta + 393216;
    float* g_bZ   = meta + 524288;
    int*   g_k    = (int*)(meta + 655360);

    for (int l = 0; l < 3; ++l) {
        const float* xin = (l == 0) ? emb : xbuf;
        linprep_kernel<<<256, 256, 0, stream>>>(xin, lin_w + (size_t)l * 16384,
                                                att_src + l * 256, att_dst + l * 256,
                                                hT, g_rank, g_E1, g_E2, g_aZ, g_bZ, g_k);
        attn_agg_fin<<<2048, 256, 0, stream>>>(hT, g_rank, g_E1, g_E2, g_aZ, g_bZ, g_k,
                                               conv_b + l * 64, xbuf);
    }
    readout_kernel<<<64, 256, 0, stream>>>(xbuf, readout_w, readout_b, out);
}

// Round 12
// 231.632 us; speedup vs baseline: 1.2015x; 1.0186x over previous
//
#include <hip/hip_runtime.h>
#include <math.h>

// Problem constants (fixed by reference): B=64, N=512, D=64, H=4, C=64, L=3
// Workspace layout (floats), ws >= 256 MB:
//   xbuf [0 .. 2097152)         : layer activations x (8 MB)
//   hT   [2097152 .. 10485760)  : h TRANSPOSED [head][c][b*512+n] (32 MB)
//   meta [10485760 .. 11534336) : prep metadata (4 MB)
// History: R23 = 237.2; R27 = 235.9 BEST (agg XCD swizzle id%8==b%8, T1
// mechanism validated: +1.3us). Mega arc DEAD; agg internals (R20/R21/R25)
// neutral; occupancy ledger complete (R15 266 / R23 237 / R24 532 / R26 278).
// R28 (this): two bit-identical tweaks on the validated mechanisms:
//   1. linprep XCD swizzle (id%8 == b%8): R26 counters showed FETCH ~39MB =
//      4x x-overfetch (4 head-blocks of b on 4 different XCDs each fetch
//      x[b] 128KB). Same-XCD grouping -> x fetched once per b.
//   2. meta packing: (E1,E2) -> float2 g_E12, (aZ,bZ) -> float2 g_ab.
//      Same bytes/values; halves meta load messages in agg fill+query.
// Decision rule: >=235.9 -> revert bundle, declare ~236 the practical floor.

using short8  = __attribute__((ext_vector_type(8))) short;
using floatx4 = __attribute__((ext_vector_type(4))) float;

__device__ inline unsigned short f2bf(float f) {
    union { float f; unsigned u; } v; v.f = f;
    unsigned u = v.u + 0x7FFFu + ((v.u >> 16) & 1u);   // round-to-nearest-even
    return (unsigned short)(u >> 16);
}
__device__ inline float bf2f(unsigned short s) {
    union { float f; unsigned u; } v; v.u = ((unsigned)s) << 16;
    return v.f;
}

// 8 floats (two float4) -> split-bf16 hi/lo short8 fragments, in registers.
__device__ inline void cvt8(const float4 a, const float4 b, short8& hi, short8& lo) {
    float f[8] = {a.x, a.y, a.z, a.w, b.x, b.y, b.z, b.w};
    short8 H, L;
#pragma unroll
    for (int i = 0; i < 8; ++i) {
        unsigned short h = f2bf(f[i]);
        H[i] = (short)h;
        L[i] = (short)f2bf(f[i] - bf2f(h));
    }
    hi = H; lo = L;
}

// ---------------------------------------------------------------------------
// Kernel A+B1 fused: linprep v2 (R23 body) + R28 XCD swizzle (id%8 == b%8):
// the 4 head-blocks of each b share x[b] (128KB) -> land on ONE XCD L2.
// grid 256, 256 threads.
// ---------------------------------------------------------------------------
__global__ __launch_bounds__(256) void linprep_kernel(const float* __restrict__ x,
                                                      const float* __restrict__ W,
                                                      const float* __restrict__ att_src,
                                                      const float* __restrict__ att_dst,
                                                      float* __restrict__ hT,
                                                      int* __restrict__ g_rank,
                                                      float2* __restrict__ g_E12,
                                                      float2* __restrict__ g_ab,
                                                      int* __restrict__ g_k) {
    __shared__ unsigned short WH[64 * 72], WL[64 * 72];
    __shared__ float sA[512], dA[512];      // s/d dots (then sA sorted in place)
    __shared__ int   s_idxE[512];
    __shared__ float z1suf[513], z2pre[513];
    __shared__ float wred[8];

    const int t  = threadIdx.x;
    // R28 bijective swizzle: id%8 = b%8 (4 head-blocks of b on one XCD).
    const int r8 = blockIdx.x & 7;
    const int q  = blockIdx.x >> 3;       // 0..31
    const int ct = q & 3;                 // head
    const int b  = ((q >> 2) << 3) | r8;  // 0..63
    const int bh = b * 4 + ct;            // meta layout index (unchanged)
    const int c0 = ct * 64;

    // ---- W staging + convert, ONCE per block ----
#pragma unroll
    for (int qq = 0; qq < 4; ++qq) {
        int f = qq * 256 + t;
        int wrow = f >> 4, d4 = f & 15;
        float4 v = *(const float4*)(W + (size_t)(c0 + wrow) * 64 + d4 * 4);
        unsigned short h0 = f2bf(v.x), h1 = f2bf(v.y), h2 = f2bf(v.z), h3 = f2bf(v.w);
        ushort4 hi = make_ushort4(h0, h1, h2, h3);
        ushort4 lo = make_ushort4(f2bf(v.x - bf2f(h0)), f2bf(v.y - bf2f(h1)),
                                  f2bf(v.z - bf2f(h2)), f2bf(v.w - bf2f(h3)));
        *(ushort4*)&WH[wrow * 72 + d4 * 4] = hi;
        *(ushort4*)&WL[wrow * 72 + d4 * 4] = lo;
    }
    __syncthreads();

    const int lane = t & 63, wv = t >> 6;
    const int mrow = lane & 15, quad = lane >> 4;

    // ---- per-wave W fragments for ALL 4 channel groups ----
    short8 bhf[4][2], blf[4][2];
#pragma unroll
    for (int g = 0; g < 4; ++g)
#pragma unroll
        for (int kk = 0; kk < 2; ++kk) {
            int ko = kk * 32 + quad * 8;
            bhf[g][kk] = *(const short8*)&WH[(g * 16 + mrow) * 72 + ko];
            blf[g][kk] = *(const short8*)&WL[(g * 16 + mrow) * 72 + ko];
        }
    float as_g[4], ad_g[4];
#pragma unroll
    for (int g = 0; g < 4; ++g) {
        as_g[g] = att_src[c0 + g * 16 + mrow];
        ad_g[g] = att_dst[c0 + g * 16 + mrow];
    }

    // ---- wave-independent tile loop: wave wv owns tiles wv, wv+4, ..., wv+28
    const float* xbase = x + (size_t)(b * 512 + mrow) * 64 + quad * 8;
    float4 nxa = *(const float4*)(xbase + (size_t)wv * 1024);
    float4 nxb = *(const float4*)(xbase + (size_t)wv * 1024 + 4);
    float4 nxc = *(const float4*)(xbase + (size_t)wv * 1024 + 32);
    float4 nxd = *(const float4*)(xbase + (size_t)wv * 1024 + 36);

#pragma unroll 1
    for (int tl = wv; tl < 32; tl += 4) {
        float4 xa = nxa, xb = nxb, xc = nxc, xd = nxd;
        if (tl + 4 < 32) {
            const float* nb = xbase + (size_t)(tl + 4) * 1024;
            nxa = *(const float4*)(nb);
            nxb = *(const float4*)(nb + 4);
            nxc = *(const float4*)(nb + 32);
            nxd = *(const float4*)(nb + 36);
        }
        short8 ah0, al0, ah1, al1;
        cvt8(xa, xb, ah0, al0);
        cvt8(xc, xd, ah1, al1);

        floatx4 acc[4];
#pragma unroll
        for (int g = 0; g < 4; ++g) {
            floatx4 a = {0.f, 0.f, 0.f, 0.f};
            a = __builtin_amdgcn_mfma_f32_16x16x32_bf16(ah0, bhf[g][0], a, 0, 0, 0);
            a = __builtin_amdgcn_mfma_f32_16x16x32_bf16(ah1, bhf[g][1], a, 0, 0, 0);
            a = __builtin_amdgcn_mfma_f32_16x16x32_bf16(ah0, blf[g][0], a, 0, 0, 0);
            a = __builtin_amdgcn_mfma_f32_16x16x32_bf16(ah1, blf[g][1], a, 0, 0, 0);
            a = __builtin_amdgcn_mfma_f32_16x16x32_bf16(al0, bhf[g][0], a, 0, 0, 0);
            a = __builtin_amdgcn_mfma_f32_16x16x32_bf16(al1, bhf[g][1], a, 0, 0, 0);
            acc[g] = a;
        }

        const int r0 = b * 512 + tl * 16;
#pragma unroll
        for (int g = 0; g < 4; ++g) {
            *(float4*)&hT[(size_t)(ct * 64 + g * 16 + mrow) * 32768 + r0 + quad * 4] =
                make_float4(acc[g][0], acc[g][1], acc[g][2], acc[g][3]);
        }

        float ps[4], pd[4];
#pragma unroll
        for (int reg = 0; reg < 4; ++reg) {
            ps[reg] = acc[0][reg] * as_g[0] + acc[1][reg] * as_g[1]
                    + acc[2][reg] * as_g[2] + acc[3][reg] * as_g[3];
            pd[reg] = acc[0][reg] * ad_g[0] + acc[1][reg] * ad_g[1]
                    + acc[2][reg] * ad_g[2] + acc[3][reg] * ad_g[3];
        }
#pragma unroll
        for (int m = 1; m <= 8; m <<= 1) {
#pragma unroll
            for (int reg = 0; reg < 4; ++reg) {
                ps[reg] += __shfl_xor(ps[reg], m, 64);
                pd[reg] += __shfl_xor(pd[reg], m, 64);
            }
        }
        if (mrow < 4) {
            sA[tl * 16 + quad * 4 + mrow] = ps[mrow];
            dA[tl * 16 + quad * 4 + mrow] = pd[mrow];
        }
    }
    __syncthreads();

    // ======================= prep body (verbatim) ==========================
    const int wid = t >> 6;

    float dreg[2];
    for (int rr = 0; rr < 2; ++rr) dreg[rr] = dA[t + rr * 256];

    float v0 = sA[2 * t], v1 = sA[2 * t + 1];
    int id0 = 2 * t, id1 = 2 * t + 1;
    for (int k = 2; k <= 512; k <<= 1) {
        for (int j = k >> 1; j >= 1; j >>= 1) {
            bool asc = ((t & (k >> 1)) == 0);
            if (j == 1) {
                bool sw = asc ? (v0 > v1) : (v0 < v1);
                if (sw) { float tv = v0; v0 = v1; v1 = tv; int ti = id0; id0 = id1; id1 = ti; }
            } else if (j <= 64) {
                int m = j >> 1;
                float w0 = __shfl_xor(v0, m, 64);
                int  wi0 = __shfl_xor(id0, m, 64);
                float w1 = __shfl_xor(v1, m, 64);
                int  wi1 = __shfl_xor(id1, m, 64);
                bool low = ((t & m) == 0);
                bool wantmin = (low == asc);
                if (wantmin ? (w0 < v0) : (w0 > v0)) { v0 = w0; id0 = wi0; }
                if (wantmin ? (w1 < v1) : (w1 > v1)) { v1 = w1; id1 = wi1; }
            } else {
                int m = j >> 1;
                sA[2 * t] = v0; sA[2 * t + 1] = v1;
                s_idxE[2 * t] = id0; s_idxE[2 * t + 1] = id1;
                __syncthreads();
                int tp = t ^ m;
                float w0 = sA[2 * tp], w1 = sA[2 * tp + 1];
                int wi0 = s_idxE[2 * tp], wi1 = s_idxE[2 * tp + 1];
                bool low = ((t & m) == 0);
                bool wantmin = (low == asc);
                if (wantmin ? (w0 < v0) : (w0 > v0)) { v0 = w0; id0 = wi0; }
                if (wantmin ? (w1 < v1) : (w1 > v1)) { v1 = w1; id1 = wi1; }
                __syncthreads();
            }
        }
    }

    sA[2 * t] = v0; sA[2 * t + 1] = v1;
    __syncthreads();
    const float M = sA[511];
    float e1_0 = __expf(v0 - M), e1_1 = __expf(v1 - M);
    float e2_0 = __expf(0.2f * (v0 - M)), e2_1 = __expf(0.2f * (v1 - M));
    {
        const int base = bh * 512;
        g_E12[base + id0] = make_float2(e1_0, e2_0);   // packed, same values
        g_E12[base + id1] = make_float2(e1_1, e2_1);
        g_rank[base + id0] = 2 * t;  g_rank[base + id1] = 2 * t + 1;
    }

    float S1 = e1_0 + e1_1, S2 = e2_0 + e2_1;
    float i1 = S1, i2 = S2;
    for (int off = 1; off < 64; off <<= 1) {
        float u1 = __shfl_up(i1, off, 64);
        float u2 = __shfl_up(i2, off, 64);
        if (lane >= off) { i1 += u1; i2 += u2; }
    }
    if (lane == 63) { wred[wid] = i1; wred[4 + wid] = i2; }
    __syncthreads();
    float off1 = 0.f, off2 = 0.f;
    for (int w = 0; w < wid; ++w) { off1 += wred[w]; off2 += wred[4 + w]; }
    const float T1 = wred[0] + wred[1] + wred[2] + wred[3];
    const float T2 = wred[4] + wred[5] + wred[6] + wred[7];
    float pre1 = off1 + i1 - S1;
    float pre2 = off2 + i2 - S2;
    z1suf[2 * t] = T1 - pre1;
    z1suf[2 * t + 1] = T1 - pre1 - e1_0;
    z2pre[2 * t] = pre2;
    z2pre[2 * t + 1] = pre2 + e2_0;
    if (t == 0) { z1suf[512] = 0.f; z2pre[512] = T2; }
    __syncthreads();

    for (int rr = 0; rr < 2; ++rr) {
        int i = t + rr * 256;
        float d = dreg[rr];
        int lo = 0, hi = 512;
        while (lo < hi) {
            int mid = (lo + hi) >> 1;
            if (d + sA[mid] >= 0.f) hi = mid; else lo = mid + 1;
        }
        int k = lo;
        float g = d + M;
        float G = (g >= 0.f) ? g : 0.2f * g;
        float al = __expf(g - G);
        float be = __expf(0.2f * g - G);
        float Z = al * z1suf[k] + be * z2pre[k];
        float inv = 1.0f / Z;
        g_ab[bh * 512 + i] = make_float2(al * inv, be * inv);   // packed
        g_k[bh * 512 + i]  = k;
    }
}

// ---------------------------------------------------------------------------
// Kernel B2: attn_agg_fin v7 + R27 XCD swizzle + R28 packed meta.
// grid = 2048 blocks, 256 thr (4 waves = 4 heads).
// ---------------------------------------------------------------------------
__global__ __launch_bounds__(256) void attn_agg_fin(const float* __restrict__ hT,
                                                    const int* __restrict__ g_rank,
                                                    const float2* __restrict__ g_E12,
                                                    const float2* __restrict__ g_ab,
                                                    const int* __restrict__ g_k,
                                                    const float* __restrict__ bias,
                                                    float* __restrict__ x) {
    // R27 bijective swizzle: id%8 = b%8.
    const int r8 = blockIdx.x & 7;
    const int qq = blockIdx.x >> 3;
    const int cg = qq & 31;                // 0..31
    const int b  = ((qq >> 5) << 3) | r8;  // 0..63
    const int c0 = cg * 2;
    const int t = threadIdx.x;
    const int lane = t & 63, wv = t >> 6;  // wv = head 0..3

    __shared__ float A1[4][2][512], A2[4][2][512];
    __shared__ float tots[4][2];

    {
        const int bh = b * 4 + wv;
        const int base = bh * 512;
        const float* hTb = hT + (size_t)(wv * 64 + c0) * 32768 + (size_t)b * 512;
#pragma unroll
        for (int it = 0; it < 8; ++it) {
            int j = it * 64 + lane;
            int rk = g_rank[base + j];
            float2 e12 = g_E12[base + j];        // packed (E1,E2)
            float h0 = hTb[j];
            float h1 = hTb[32768 + j];
            int pk = ((rk & 7) << 6) | (rk >> 3);
            A1[wv][0][pk] = e12.x * h0;  A2[wv][0][pk] = e12.y * h0;
            A1[wv][1][pk] = e12.x * h1;  A2[wv][1][pk] = e12.y * h1;
        }
#pragma unroll
        for (int cc = 0; cc < 2; ++cc) {
            float v1[8], v2[8];
#pragma unroll
            for (int i = 0; i < 8; ++i) {
                v1[i] = A1[wv][cc][i * 64 + lane];
                v2[i] = A2[wv][cc][i * 64 + lane];
            }
            float s1 = 0.f, s2 = 0.f;
#pragma unroll
            for (int i = 0; i < 8; ++i) { s1 += v1[i]; s2 += v2[i]; }
            float suf = s1;
#pragma unroll
            for (int off = 1; off < 64; off <<= 1) {
                float u = __shfl_down(suf, off, 64);
                if (lane + off < 64) suf += u;
            }
            float run = suf - s1;
            float pre = s2;
#pragma unroll
            for (int off = 1; off < 64; off <<= 1) {
                float u = __shfl_up(pre, off, 64);
                if (lane >= off) pre += u;
            }
            float run2 = pre - s2;
            if (lane == 63) tots[wv][cc] = pre;
#pragma unroll
            for (int i = 7; i >= 0; --i) { run += v1[i]; v1[i] = run; }
#pragma unroll
            for (int i = 0; i < 8; ++i) { float tv = v2[i]; v2[i] = run2; run2 += tv; }
#pragma unroll
            for (int i = 0; i < 8; ++i) {
                A1[wv][cc][i * 64 + lane] = v1[i];
                A2[wv][cc][i * 64 + lane] = v2[i];
            }
        }
    }
    __syncthreads();

    const float bv0 = bias[c0], bv1 = bias[c0 + 1];
#pragma unroll
    for (int rr = 0; rr < 2; ++rr) {
        const int i = t + rr * 256;
        float a0 = 0.f, a1 = 0.f;
#pragma unroll
        for (int head = 0; head < 4; ++head) {
            const int base = (b * 4 + head) * 512;
            float2 ab = g_ab[base + i];          // packed (aZ,bZ)
            int k = g_k[base + i];
            if (k < 512) {
                int pk = ((k & 7) << 6) | (k >> 3);
                a0 += ab.x * A1[head][0][pk] + ab.y * A2[head][0][pk];
                a1 += ab.x * A1[head][1][pk] + ab.y * A2[head][1][pk];
            } else {
                a0 += ab.y * tots[head][0];
                a1 += ab.y * tots[head][1];
            }
        }
        float2 o = make_float2(fmaxf(0.25f * a0 + bv0, 0.f),
                               fmaxf(0.25f * a1 + bv1, 0.f));
        *(float2*)&x[(size_t)(b * 512 + i) * 64 + c0] = o;
    }
}

// ---------------------------------------------------------------------------
// Kernel D: readout (unchanged)
// ---------------------------------------------------------------------------
__global__ __launch_bounds__(256) void readout_kernel(const float* __restrict__ x,
                                                      const float* __restrict__ rw,
                                                      const float* __restrict__ rb,
                                                      float* __restrict__ out) {
    __shared__ float red[4][64];
    __shared__ float pooled[64];
    int b = blockIdx.x, t = threadIdx.x;
    int c = t & 63, q = t >> 6;
    float acc = 0.f;
    for (int n = q; n < 512; n += 4) acc += x[((size_t)b * 512 + n) * 64 + c];
    red[q][c] = acc;
    __syncthreads();
    if (t < 64) pooled[t] = (red[0][t] + red[1][t] + red[2][t] + red[3][t]) * (1.0f / 512.0f);
    __syncthreads();
    if (t < 64) {
        float a = rb[t];
        for (int cc = 0; cc < 64; ++cc) a += pooled[cc] * rw[t * 64 + cc];
        out[b * 64 + t] = a;
    }
}

extern "C" void kernel_launch(void* const* d_in, const int* in_sizes, int n_in,
                              void* d_out, int out_size, void* d_ws, size_t ws_size,
                              hipStream_t stream) {
    const float* emb       = (const float*)d_in[0];
    const float* lin_w     = (const float*)d_in[1];
    const float* att_src   = (const float*)d_in[2];
    const float* att_dst   = (const float*)d_in[3];
    const float* conv_b    = (const float*)d_in[4];
    const float* readout_w = (const float*)d_in[5];
    const float* readout_b = (const float*)d_in[6];
    float* out = (float*)d_out;

    float* ws   = (float*)d_ws;
    float* xbuf = ws;                    // 8 MB
    float* hT   = ws + 2097152;          // 32 MB, [head][c][b*512+n]
    float* meta = ws + 10485760;         // 4 MB

    int*    g_rank = (int*)meta;                 // [256*512]
    float2* g_E12  = (float2*)(meta + 131072);   // [256*512] packed (E1,E2)
    float2* g_ab   = (float2*)(meta + 393216);   // [256*512] packed (aZ,bZ)
    int*    g_k    = (int*)(meta + 655360);

    for (int l = 0; l < 3; ++l) {
        const float* xin = (l == 0) ? emb : xbuf;
        linprep_kernel<<<256, 256, 0, stream>>>(xin, lin_w + (size_t)l * 16384,
                                                att_src + l * 256, att_dst + l * 256,
                                                hT, g_rank, g_E12, g_ab, g_k);
        attn_agg_fin<<<2048, 256, 0, stream>>>(hT, g_rank, g_E12, g_ab, g_k,
                                               conv_b + l * 64, xbuf);
    }
    readout_kernel<<<64, 256, 0, stream>>>(xbuf, readout_w, readout_b, out);
}

// Round 13
// 229.170 us; speedup vs baseline: 1.2144x; 1.0107x over previous
//
#include <hip/hip_runtime.h>
#include <math.h>

// Problem constants (fixed by reference): B=64, N=512, D=64, H=4, C=64, L=3
// Workspace layout (floats), ws >= 256 MB:
//   xbuf [0 .. 2097152)         : layer activations x (8 MB)
//   hT   [2097152 .. 10485760)  : h TRANSPOSED [head][c][b*512+n] (32 MB)
//   meta [10485760 .. 11534336) : g_rE float4[256*512] + g_abk float4[256*512]
// History: R23 237.2 -> R27 235.9 (agg XCD swizzle) -> R28 231.6 BEST
// (linprep XCD swizzle + (E1,E2)/(aZ,bZ) packing). Validated mechanisms:
// XCD-L2 grouping (x2), load-message reduction (x1), wave-independence (x1).
// R24 lesson: grid >= 256 CUs always. R26 failed at 1024thr via x4-redundant
// sort + LDS frag re-reads (confounds, not occupancy itself).
// R29 (this): two bit-identical changes:
//   a) linprep at 512 threads, grid 256: lin = 8 waves (2/SIMD, 2x latency
//      hiding), wave owns tiles wv+8k, W-frags in REGISTERS (R23 style);
//      prep runs on t<256 ONLY (no redundancy) — sort restructured to
//      unconditional barriers + act-guarded work (9 barriers, uniform).
//   b) packing round 2: (rank,E1,E2)->float4 g_rE (agg fill 2 loads->1),
//      (aZ,bZ,k)->float4 g_abk (agg query 2->1, linprep tail 2 stores->1).
// Decision rule: >=231.6 -> revert to exact R28, declare ~231 the floor.

using short8  = __attribute__((ext_vector_type(8))) short;
using floatx4 = __attribute__((ext_vector_type(4))) float;

__device__ inline unsigned short f2bf(float f) {
    union { float f; unsigned u; } v; v.f = f;
    unsigned u = v.u + 0x7FFFu + ((v.u >> 16) & 1u);   // round-to-nearest-even
    return (unsigned short)(u >> 16);
}
__device__ inline float bf2f(unsigned short s) {
    union { float f; unsigned u; } v; v.u = ((unsigned)s) << 16;
    return v.f;
}

// 8 floats (two float4) -> split-bf16 hi/lo short8 fragments, in registers.
__device__ inline void cvt8(const float4 a, const float4 b, short8& hi, short8& lo) {
    float f[8] = {a.x, a.y, a.z, a.w, b.x, b.y, b.z, b.w};
    short8 H, L;
#pragma unroll
    for (int i = 0; i < 8; ++i) {
        unsigned short h = f2bf(f[i]);
        H[i] = (short)h;
        L[i] = (short)f2bf(f[i] - bf2f(h));
    }
    hi = H; lo = L;
}

// ---------------------------------------------------------------------------
// Kernel A+B1 fused: linprep v4 (R29) — 512 threads, grid 256 (= 1 block/CU,
// 2 waves/SIMD for lin). XCD swizzle id%8==b%8 (R28). Prep on t<256 only,
// with UNCONDITIONAL barriers (9 total) + act-guarded work.
// ---------------------------------------------------------------------------
__global__ __launch_bounds__(512) void linprep_kernel(const float* __restrict__ x,
                                                      const float* __restrict__ W,
                                                      const float* __restrict__ att_src,
                                                      const float* __restrict__ att_dst,
                                                      float* __restrict__ hT,
                                                      float4* __restrict__ g_rE,
                                                      float4* __restrict__ g_abk) {
    __shared__ unsigned short WH[64 * 72], WL[64 * 72];
    __shared__ float sA[512], dA[512];      // s/d dots (then sA sorted in place)
    __shared__ int   s_idxE[512];
    __shared__ float z1suf[513], z2pre[513];
    __shared__ float wred[8];

    const int t  = threadIdx.x;
    // R28 bijective swizzle: id%8 = b%8 (4 head-blocks of b on one XCD).
    const int r8 = blockIdx.x & 7;
    const int q  = blockIdx.x >> 3;       // 0..31
    const int ct = q & 3;                 // head
    const int b  = ((q >> 2) << 3) | r8;  // 0..63
    const int bh = b * 4 + ct;            // meta layout index (unchanged)
    const int c0 = ct * 64;

    // ---- W staging + convert, ONCE per block (512 thr: 2 float4 each) ----
#pragma unroll
    for (int qq = 0; qq < 2; ++qq) {
        int f = qq * 512 + t;
        int wrow = f >> 4, d4 = f & 15;
        float4 v = *(const float4*)(W + (size_t)(c0 + wrow) * 64 + d4 * 4);
        unsigned short h0 = f2bf(v.x), h1 = f2bf(v.y), h2 = f2bf(v.z), h3 = f2bf(v.w);
        ushort4 hi = make_ushort4(h0, h1, h2, h3);
        ushort4 lo = make_ushort4(f2bf(v.x - bf2f(h0)), f2bf(v.y - bf2f(h1)),
                                  f2bf(v.z - bf2f(h2)), f2bf(v.w - bf2f(h3)));
        *(ushort4*)&WH[wrow * 72 + d4 * 4] = hi;
        *(ushort4*)&WL[wrow * 72 + d4 * 4] = lo;
    }
    __syncthreads();

    const int lane = t & 63, wv = t >> 6;   // wv = 0..7
    const int mrow = lane & 15, quad = lane >> 4;

    // ---- per-wave W fragments for ALL 4 channel groups (REGISTERS) ----
    short8 bhf[4][2], blf[4][2];
#pragma unroll
    for (int g = 0; g < 4; ++g)
#pragma unroll
        for (int kk = 0; kk < 2; ++kk) {
            int ko = kk * 32 + quad * 8;
            bhf[g][kk] = *(const short8*)&WH[(g * 16 + mrow) * 72 + ko];
            blf[g][kk] = *(const short8*)&WL[(g * 16 + mrow) * 72 + ko];
        }
    float as_g[4], ad_g[4];
#pragma unroll
    for (int g = 0; g < 4; ++g) {
        as_g[g] = att_src[c0 + g * 16 + mrow];
        ad_g[g] = att_dst[c0 + g * 16 + mrow];
    }

    // ---- lin: wave wv owns tiles wv, wv+8, wv+16, wv+24 (1-deep prefetch) --
    const float* xbase = x + (size_t)(b * 512 + mrow) * 64 + quad * 8;
    float4 nxa = *(const float4*)(xbase + (size_t)wv * 1024);
    float4 nxb = *(const float4*)(xbase + (size_t)wv * 1024 + 4);
    float4 nxc = *(const float4*)(xbase + (size_t)wv * 1024 + 32);
    float4 nxd = *(const float4*)(xbase + (size_t)wv * 1024 + 36);

#pragma unroll 1
    for (int tl = wv; tl < 32; tl += 8) {
        float4 xa = nxa, xb = nxb, xc = nxc, xd = nxd;
        if (tl + 8 < 32) {
            const float* nb = xbase + (size_t)(tl + 8) * 1024;
            nxa = *(const float4*)(nb);
            nxb = *(const float4*)(nb + 4);
            nxc = *(const float4*)(nb + 32);
            nxd = *(const float4*)(nb + 36);
        }
        short8 ah0, al0, ah1, al1;
        cvt8(xa, xb, ah0, al0);
        cvt8(xc, xd, ah1, al1);

        floatx4 acc[4];
#pragma unroll
        for (int g = 0; g < 4; ++g) {
            floatx4 a = {0.f, 0.f, 0.f, 0.f};
            a = __builtin_amdgcn_mfma_f32_16x16x32_bf16(ah0, bhf[g][0], a, 0, 0, 0);
            a = __builtin_amdgcn_mfma_f32_16x16x32_bf16(ah1, bhf[g][1], a, 0, 0, 0);
            a = __builtin_amdgcn_mfma_f32_16x16x32_bf16(ah0, blf[g][0], a, 0, 0, 0);
            a = __builtin_amdgcn_mfma_f32_16x16x32_bf16(ah1, blf[g][1], a, 0, 0, 0);
            a = __builtin_amdgcn_mfma_f32_16x16x32_bf16(al0, bhf[g][0], a, 0, 0, 0);
            a = __builtin_amdgcn_mfma_f32_16x16x32_bf16(al1, bhf[g][1], a, 0, 0, 0);
            acc[g] = a;
        }

        const int r0 = b * 512 + tl * 16;
#pragma unroll
        for (int g = 0; g < 4; ++g) {
            *(float4*)&hT[(size_t)(ct * 64 + g * 16 + mrow) * 32768 + r0 + quad * 4] =
                make_float4(acc[g][0], acc[g][1], acc[g][2], acc[g][3]);
        }

        float ps[4], pd[4];
#pragma unroll
        for (int reg = 0; reg < 4; ++reg) {
            ps[reg] = acc[0][reg] * as_g[0] + acc[1][reg] * as_g[1]
                    + acc[2][reg] * as_g[2] + acc[3][reg] * as_g[3];
            pd[reg] = acc[0][reg] * ad_g[0] + acc[1][reg] * ad_g[1]
                    + acc[2][reg] * ad_g[2] + acc[3][reg] * ad_g[3];
        }
#pragma unroll
        for (int m = 1; m <= 8; m <<= 1) {
#pragma unroll
            for (int reg = 0; reg < 4; ++reg) {
                ps[reg] += __shfl_xor(ps[reg], m, 64);
                pd[reg] += __shfl_xor(pd[reg], m, 64);
            }
        }
        if (mrow < 4) {
            sA[tl * 16 + quad * 4 + mrow] = ps[mrow];
            dA[tl * 16 + quad * 4 + mrow] = pd[mrow];
        }
    }
    __syncthreads();

    // ======================= prep body: t<256 active ========================
    // Barriers are UNCONDITIONAL (loop bounds thread-independent; 9 total);
    // all data work act-guarded. act is wave-uniform (t<256 <=> wv<4).
    const bool act = (t < 256);
    const int wid = t >> 6;               // 0..3 when act

    float dreg[2] = {0.f, 0.f};
    if (act) {
        dreg[0] = dA[t];
        dreg[1] = dA[t + 256];
    }

    float v0 = 0.f, v1 = 0.f;
    int id0 = 0, id1 = 0;
    if (act) { v0 = sA[2 * t]; v1 = sA[2 * t + 1]; id0 = 2 * t; id1 = 2 * t + 1; }

    for (int k = 2; k <= 512; k <<= 1) {
        for (int j = k >> 1; j >= 1; j >>= 1) {
            bool asc = ((t & (k >> 1)) == 0);
            if (j == 1) {
                if (act) {
                    bool sw = asc ? (v0 > v1) : (v0 < v1);
                    if (sw) { float tv = v0; v0 = v1; v1 = tv; int ti = id0; id0 = id1; id1 = ti; }
                }
            } else if (j <= 64) {
                if (act) {
                    int m = j >> 1;
                    float w0 = __shfl_xor(v0, m, 64);
                    int  wi0 = __shfl_xor(id0, m, 64);
                    float w1 = __shfl_xor(v1, m, 64);
                    int  wi1 = __shfl_xor(id1, m, 64);
                    bool low = ((t & m) == 0);
                    bool wantmin = (low == asc);
                    if (wantmin ? (w0 < v0) : (w0 > v0)) { v0 = w0; id0 = wi0; }
                    if (wantmin ? (w1 < v1) : (w1 > v1)) { v1 = w1; id1 = wi1; }
                }
            } else {
                int m = j >> 1;
                if (act) {
                    sA[2 * t] = v0; sA[2 * t + 1] = v1;
                    s_idxE[2 * t] = id0; s_idxE[2 * t + 1] = id1;
                }
                __syncthreads();                       // (x6 over 3 stages)
                if (act) {
                    int tp = t ^ m;
                    float w0 = sA[2 * tp], w1 = sA[2 * tp + 1];
                    int wi0 = s_idxE[2 * tp], wi1 = s_idxE[2 * tp + 1];
                    bool low = ((t & m) == 0);
                    bool wantmin = (low == asc);
                    if (wantmin ? (w0 < v0) : (w0 > v0)) { v0 = w0; id0 = wi0; }
                    if (wantmin ? (w1 < v1) : (w1 > v1)) { v1 = w1; id1 = wi1; }
                }
                __syncthreads();
            }
        }
    }

    if (act) { sA[2 * t] = v0; sA[2 * t + 1] = v1; }
    __syncthreads();                                    // (7)
    const float M = sA[511];

    float e1_0 = 0.f, e1_1 = 0.f, e2_0 = 0.f, e2_1 = 0.f;
    if (act) {
        e1_0 = __expf(v0 - M);  e1_1 = __expf(v1 - M);
        e2_0 = __expf(0.2f * (v0 - M));  e2_1 = __expf(0.2f * (v1 - M));
        const int base = bh * 512;
        // packed (rank, E1, E2): scatter by original id (permutation, race-free)
        g_rE[base + id0] = make_float4(__int_as_float(2 * t),     e1_0, e2_0, 0.f);
        g_rE[base + id1] = make_float4(__int_as_float(2 * t + 1), e1_1, e2_1, 0.f);
    }

    float S1 = e1_0 + e1_1, S2 = e2_0 + e2_1;
    float i1 = S1, i2 = S2;
    if (act) {
        for (int off = 1; off < 64; off <<= 1) {
            float u1 = __shfl_up(i1, off, 64);
            float u2 = __shfl_up(i2, off, 64);
            if (lane >= off) { i1 += u1; i2 += u2; }
        }
        if (lane == 63) { wred[wid] = i1; wred[4 + wid] = i2; }
    }
    __syncthreads();                                    // (8)
    if (act) {
        float off1 = 0.f, off2 = 0.f;
        for (int w = 0; w < wid; ++w) { off1 += wred[w]; off2 += wred[4 + w]; }
        const float T1 = wred[0] + wred[1] + wred[2] + wred[3];
        const float T2 = wred[4] + wred[5] + wred[6] + wred[7];
        float pre1 = off1 + i1 - S1;
        float pre2 = off2 + i2 - S2;
        z1suf[2 * t] = T1 - pre1;
        z1suf[2 * t + 1] = T1 - pre1 - e1_0;
        z2pre[2 * t] = pre2;
        z2pre[2 * t + 1] = pre2 + e2_0;
        if (t == 0) { z1suf[512] = 0.f; z2pre[512] = T2; }
    }
    __syncthreads();                                    // (9)

    if (act) {
        for (int rr = 0; rr < 2; ++rr) {
            int i = t + rr * 256;
            float d = dreg[rr];
            int lo = 0, hi = 512;
            while (lo < hi) {
                int mid = (lo + hi) >> 1;
                if (d + sA[mid] >= 0.f) hi = mid; else lo = mid + 1;
            }
            int k = lo;
            float g = d + M;
            float G = (g >= 0.f) ? g : 0.2f * g;
            float al = __expf(g - G);
            float be = __expf(0.2f * g - G);
            float Z = al * z1suf[k] + be * z2pre[k];
            float inv = 1.0f / Z;
            // packed (aZ, bZ, k)
            g_abk[bh * 512 + i] = make_float4(al * inv, be * inv,
                                              __int_as_float(k), 0.f);
        }
    }
}

// ---------------------------------------------------------------------------
// Kernel B2: attn_agg_fin v7 + R27 XCD swizzle + R29 float4 packed meta.
// grid = 2048 blocks, 256 thr (4 waves = 4 heads).
// ---------------------------------------------------------------------------
__global__ __launch_bounds__(256) void attn_agg_fin(const float* __restrict__ hT,
                                                    const float4* __restrict__ g_rE,
                                                    const float4* __restrict__ g_abk,
                                                    const float* __restrict__ bias,
                                                    float* __restrict__ x) {
    // R27 bijective swizzle: id%8 = b%8.
    const int r8 = blockIdx.x & 7;
    const int qq = blockIdx.x >> 3;
    const int cg = qq & 31;                // 0..31
    const int b  = ((qq >> 5) << 3) | r8;  // 0..63
    const int c0 = cg * 2;
    const int t = threadIdx.x;
    const int lane = t & 63, wv = t >> 6;  // wv = head 0..3

    __shared__ float A1[4][2][512], A2[4][2][512];
    __shared__ float tots[4][2];

    {
        const int bh = b * 4 + wv;
        const int base = bh * 512;
        const float* hTb = hT + (size_t)(wv * 64 + c0) * 32768 + (size_t)b * 512;
#pragma unroll
        for (int it = 0; it < 8; ++it) {
            int j = it * 64 + lane;
            float4 rE = g_rE[base + j];          // packed (rank, E1, E2)
            int rk = __float_as_int(rE.x);
            float h0 = hTb[j];
            float h1 = hTb[32768 + j];
            int pk = ((rk & 7) << 6) | (rk >> 3);
            A1[wv][0][pk] = rE.y * h0;  A2[wv][0][pk] = rE.z * h0;
            A1[wv][1][pk] = rE.y * h1;  A2[wv][1][pk] = rE.z * h1;
        }
#pragma unroll
        for (int cc = 0; cc < 2; ++cc) {
            float v1[8], v2[8];
#pragma unroll
            for (int i = 0; i < 8; ++i) {
                v1[i] = A1[wv][cc][i * 64 + lane];
                v2[i] = A2[wv][cc][i * 64 + lane];
            }
            float s1 = 0.f, s2 = 0.f;
#pragma unroll
            for (int i = 0; i < 8; ++i) { s1 += v1[i]; s2 += v2[i]; }
            float suf = s1;
#pragma unroll
            for (int off = 1; off < 64; off <<= 1) {
                float u = __shfl_down(suf, off, 64);
                if (lane + off < 64) suf += u;
            }
            float run = suf - s1;
            float pre = s2;
#pragma unroll
            for (int off = 1; off < 64; off <<= 1) {
                float u = __shfl_up(pre, off, 64);
                if (lane >= off) pre += u;
            }
            float run2 = pre - s2;
            if (lane == 63) tots[wv][cc] = pre;
#pragma unroll
            for (int i = 7; i >= 0; --i) { run += v1[i]; v1[i] = run; }
#pragma unroll
            for (int i = 0; i < 8; ++i) { float tv = v2[i]; v2[i] = run2; run2 += tv; }
#pragma unroll
            for (int i = 0; i < 8; ++i) {
                A1[wv][cc][i * 64 + lane] = v1[i];
                A2[wv][cc][i * 64 + lane] = v2[i];
            }
        }
    }
    __syncthreads();

    const float bv0 = bias[c0], bv1 = bias[c0 + 1];
#pragma unroll
    for (int rr = 0; rr < 2; ++rr) {
        const int i = t + rr * 256;
        float a0 = 0.f, a1 = 0.f;
#pragma unroll
        for (int head = 0; head < 4; ++head) {
            const int base = (b * 4 + head) * 512;
            float4 abk = g_abk[base + i];        // packed (aZ, bZ, k)
            int k = __float_as_int(abk.z);
            if (k < 512) {
                int pk = ((k & 7) << 6) | (k >> 3);
                a0 += abk.x * A1[head][0][pk] + abk.y * A2[head][0][pk];
                a1 += abk.x * A1[head][1][pk] + abk.y * A2[head][1][pk];
            } else {
                a0 += abk.y * tots[head][0];
                a1 += abk.y * tots[head][1];
            }
        }
        float2 o = make_float2(fmaxf(0.25f * a0 + bv0, 0.f),
                               fmaxf(0.25f * a1 + bv1, 0.f));
        *(float2*)&x[(size_t)(b * 512 + i) * 64 + c0] = o;
    }
}

// ---------------------------------------------------------------------------
// Kernel D: readout (unchanged)
// ---------------------------------------------------------------------------
__global__ __launch_bounds__(256) void readout_kernel(const float* __restrict__ x,
                                                      const float* __restrict__ rw,
                                                      const float* __restrict__ rb,
                                                      float* __restrict__ out) {
    __shared__ float red[4][64];
    __shared__ float pooled[64];
    int b = blockIdx.x, t = threadIdx.x;
    int c = t & 63, q = t >> 6;
    float acc = 0.f;
    for (int n = q; n < 512; n += 4) acc += x[((size_t)b * 512 + n) * 64 + c];
    red[q][c] = acc;
    __syncthreads();
    if (t < 64) pooled[t] = (red[0][t] + red[1][t] + red[2][t] + red[3][t]) * (1.0f / 512.0f);
    __syncthreads();
    if (t < 64) {
        float a = rb[t];
        for (int cc = 0; cc < 64; ++cc) a += pooled[cc] * rw[t * 64 + cc];
        out[b * 64 + t] = a;
    }
}

extern "C" void kernel_launch(void* const* d_in, const int* in_sizes, int n_in,
                              void* d_out, int out_size, void* d_ws, size_t ws_size,
                              hipStream_t stream) {
    const float* emb       = (const float*)d_in[0];
    const float* lin_w     = (const float*)d_in[1];
    const float* att_src   = (const float*)d_in[2];
    const float* att_dst   = (const float*)d_in[3];
    const float* conv_b    = (const float*)d_in[4];
    const float* readout_w = (const float*)d_in[5];
    const float* readout_b = (const float*)d_in[6];
    float* out = (float*)d_out;

    float* ws   = (float*)d_ws;
    float* xbuf = ws;                    // 8 MB
    float* hT   = ws + 2097152;          // 32 MB, [head][c][b*512+n]
    float* meta = ws + 10485760;         // 4 MB

    float4* g_rE  = (float4*)meta;                 // [256*512] (rank,E1,E2,-)
    float4* g_abk = (float4*)(meta + 524288);      // [256*512] (aZ,bZ,k,-)

    for (int l = 0; l < 3; ++l) {
        const float* xin = (l == 0) ? emb : xbuf;
        linprep_kernel<<<256, 512, 0, stream>>>(xin, lin_w + (size_t)l * 16384,
                                                att_src + l * 256, att_dst + l * 256,
                                                hT, g_rE, g_abk);
        attn_agg_fin<<<2048, 256, 0, stream>>>(hT, g_rE, g_abk,
                                               conv_b + l * 64, xbuf);
    }
    readout_kernel<<<64, 256, 0, stream>>>(xbuf, readout_w, readout_b, out);
}

// Round 14
// 201.387 us; speedup vs baseline: 1.3819x; 1.1380x over previous
//
#include <hip/hip_runtime.h>
#include <math.h>

// Problem constants (fixed by reference): B=64, N=512, D=64, H=4, C=64, L=3
// Workspace layout (floats), ws >= 256 MB:
//   xbuf [0 .. 2097152)          : layer activations x (8 MB)
//   hT   [2097152 .. 10485760)   : h TRANSPOSED [head][c][b*512+n] (32 MB)
//   meta [10485760 .. 11534336)  : g_rE float4 + g_abk float4 (4 MB)
//   pooled [11534336 .. +4096)   : per-(b,c) over-n sums (16 KB)
// History: R23 237.2 -> R27 235.9 -> R28 231.6 -> R29 229.2 BEST.
// Validated mechanisms: XCD-L2 grouping (x2), load-message reduction (x2),
// wave-depth w/o confounds (x1). Mega arc DEAD; R24 lesson: grid >= 256 CUs.
// R30 (this): message-reduction applied to agg's LDS + readout retire:
//   a) A1/A2 -> interleaved float2 A12[4][2][512]: every LDS access pair
//      becomes one b64 op (fill scatter, scan IO, query). Bit-identical.
//   b) agg block (b,cg) exclusively owns channels c0,c0+1 of b -> emits
//      complete pooled[b][c] sums (butterfly + 4-wave reduce, no atomics);
//      readout reads 16KB pooled instead of 8MB xbuf. Pool sum ORDER
//      changes (tree vs 4-chain) -> absmax may drift to ~1e-5; fine.
// Decision rule: >=229.2 -> revert to exact R29.

using short8  = __attribute__((ext_vector_type(8))) short;
using floatx4 = __attribute__((ext_vector_type(4))) float;

__device__ inline unsigned short f2bf(float f) {
    union { float f; unsigned u; } v; v.f = f;
    unsigned u = v.u + 0x7FFFu + ((v.u >> 16) & 1u);   // round-to-nearest-even
    return (unsigned short)(u >> 16);
}
__device__ inline float bf2f(unsigned short s) {
    union { float f; unsigned u; } v; v.u = ((unsigned)s) << 16;
    return v.f;
}

// 8 floats (two float4) -> split-bf16 hi/lo short8 fragments, in registers.
__device__ inline void cvt8(const float4 a, const float4 b, short8& hi, short8& lo) {
    float f[8] = {a.x, a.y, a.z, a.w, b.x, b.y, b.z, b.w};
    short8 H, L;
#pragma unroll
    for (int i = 0; i < 8; ++i) {
        unsigned short h = f2bf(f[i]);
        H[i] = (short)h;
        L[i] = (short)f2bf(f[i] - bf2f(h));
    }
    hi = H; lo = L;
}

// ---------------------------------------------------------------------------
// Kernel A+B1 fused: linprep v4 (R29, UNCHANGED) — 512 threads, grid 256,
// XCD swizzle id%8==b%8, prep on t<256 with unconditional barriers.
// ---------------------------------------------------------------------------
__global__ __launch_bounds__(512) void linprep_kernel(const float* __restrict__ x,
                                                      const float* __restrict__ W,
                                                      const float* __restrict__ att_src,
                                                      const float* __restrict__ att_dst,
                                                      float* __restrict__ hT,
                                                      float4* __restrict__ g_rE,
                                                      float4* __restrict__ g_abk) {
    __shared__ unsigned short WH[64 * 72], WL[64 * 72];
    __shared__ float sA[512], dA[512];      // s/d dots (then sA sorted in place)
    __shared__ int   s_idxE[512];
    __shared__ float z1suf[513], z2pre[513];
    __shared__ float wred[8];

    const int t  = threadIdx.x;
    // R28 bijective swizzle: id%8 = b%8 (4 head-blocks of b on one XCD).
    const int r8 = blockIdx.x & 7;
    const int q  = blockIdx.x >> 3;       // 0..31
    const int ct = q & 3;                 // head
    const int b  = ((q >> 2) << 3) | r8;  // 0..63
    const int bh = b * 4 + ct;            // meta layout index (unchanged)
    const int c0 = ct * 64;

    // ---- W staging + convert, ONCE per block (512 thr: 2 float4 each) ----
#pragma unroll
    for (int qq = 0; qq < 2; ++qq) {
        int f = qq * 512 + t;
        int wrow = f >> 4, d4 = f & 15;
        float4 v = *(const float4*)(W + (size_t)(c0 + wrow) * 64 + d4 * 4);
        unsigned short h0 = f2bf(v.x), h1 = f2bf(v.y), h2 = f2bf(v.z), h3 = f2bf(v.w);
        ushort4 hi = make_ushort4(h0, h1, h2, h3);
        ushort4 lo = make_ushort4(f2bf(v.x - bf2f(h0)), f2bf(v.y - bf2f(h1)),
                                  f2bf(v.z - bf2f(h2)), f2bf(v.w - bf2f(h3)));
        *(ushort4*)&WH[wrow * 72 + d4 * 4] = hi;
        *(ushort4*)&WL[wrow * 72 + d4 * 4] = lo;
    }
    __syncthreads();

    const int lane = t & 63, wv = t >> 6;   // wv = 0..7
    const int mrow = lane & 15, quad = lane >> 4;

    // ---- per-wave W fragments for ALL 4 channel groups (REGISTERS) ----
    short8 bhf[4][2], blf[4][2];
#pragma unroll
    for (int g = 0; g < 4; ++g)
#pragma unroll
        for (int kk = 0; kk < 2; ++kk) {
            int ko = kk * 32 + quad * 8;
            bhf[g][kk] = *(const short8*)&WH[(g * 16 + mrow) * 72 + ko];
            blf[g][kk] = *(const short8*)&WL[(g * 16 + mrow) * 72 + ko];
        }
    float as_g[4], ad_g[4];
#pragma unroll
    for (int g = 0; g < 4; ++g) {
        as_g[g] = att_src[c0 + g * 16 + mrow];
        ad_g[g] = att_dst[c0 + g * 16 + mrow];
    }

    // ---- lin: wave wv owns tiles wv, wv+8, wv+16, wv+24 (1-deep prefetch) --
    const float* xbase = x + (size_t)(b * 512 + mrow) * 64 + quad * 8;
    float4 nxa = *(const float4*)(xbase + (size_t)wv * 1024);
    float4 nxb = *(const float4*)(xbase + (size_t)wv * 1024 + 4);
    float4 nxc = *(const float4*)(xbase + (size_t)wv * 1024 + 32);
    float4 nxd = *(const float4*)(xbase + (size_t)wv * 1024 + 36);

#pragma unroll 1
    for (int tl = wv; tl < 32; tl += 8) {
        float4 xa = nxa, xb = nxb, xc = nxc, xd = nxd;
        if (tl + 8 < 32) {
            const float* nb = xbase + (size_t)(tl + 8) * 1024;
            nxa = *(const float4*)(nb);
            nxb = *(const float4*)(nb + 4);
            nxc = *(const float4*)(nb + 32);
            nxd = *(const float4*)(nb + 36);
        }
        short8 ah0, al0, ah1, al1;
        cvt8(xa, xb, ah0, al0);
        cvt8(xc, xd, ah1, al1);

        floatx4 acc[4];
#pragma unroll
        for (int g = 0; g < 4; ++g) {
            floatx4 a = {0.f, 0.f, 0.f, 0.f};
            a = __builtin_amdgcn_mfma_f32_16x16x32_bf16(ah0, bhf[g][0], a, 0, 0, 0);
            a = __builtin_amdgcn_mfma_f32_16x16x32_bf16(ah1, bhf[g][1], a, 0, 0, 0);
            a = __builtin_amdgcn_mfma_f32_16x16x32_bf16(ah0, blf[g][0], a, 0, 0, 0);
            a = __builtin_amdgcn_mfma_f32_16x16x32_bf16(ah1, blf[g][1], a, 0, 0, 0);
            a = __builtin_amdgcn_mfma_f32_16x16x32_bf16(al0, bhf[g][0], a, 0, 0, 0);
            a = __builtin_amdgcn_mfma_f32_16x16x32_bf16(al1, bhf[g][1], a, 0, 0, 0);
            acc[g] = a;
        }

        const int r0 = b * 512 + tl * 16;
#pragma unroll
        for (int g = 0; g < 4; ++g) {
            *(float4*)&hT[(size_t)(ct * 64 + g * 16 + mrow) * 32768 + r0 + quad * 4] =
                make_float4(acc[g][0], acc[g][1], acc[g][2], acc[g][3]);
        }

        float ps[4], pd[4];
#pragma unroll
        for (int reg = 0; reg < 4; ++reg) {
            ps[reg] = acc[0][reg] * as_g[0] + acc[1][reg] * as_g[1]
                    + acc[2][reg] * as_g[2] + acc[3][reg] * as_g[3];
            pd[reg] = acc[0][reg] * ad_g[0] + acc[1][reg] * ad_g[1]
                    + acc[2][reg] * ad_g[2] + acc[3][reg] * ad_g[3];
        }
#pragma unroll
        for (int m = 1; m <= 8; m <<= 1) {
#pragma unroll
            for (int reg = 0; reg < 4; ++reg) {
                ps[reg] += __shfl_xor(ps[reg], m, 64);
                pd[reg] += __shfl_xor(pd[reg], m, 64);
            }
        }
        if (mrow < 4) {
            sA[tl * 16 + quad * 4 + mrow] = ps[mrow];
            dA[tl * 16 + quad * 4 + mrow] = pd[mrow];
        }
    }
    __syncthreads();

    // ======================= prep body: t<256 active ========================
    const bool act = (t < 256);
    const int wid = t >> 6;               // 0..3 when act

    float dreg[2] = {0.f, 0.f};
    if (act) {
        dreg[0] = dA[t];
        dreg[1] = dA[t + 256];
    }

    float v0 = 0.f, v1 = 0.f;
    int id0 = 0, id1 = 0;
    if (act) { v0 = sA[2 * t]; v1 = sA[2 * t + 1]; id0 = 2 * t; id1 = 2 * t + 1; }

    for (int k = 2; k <= 512; k <<= 1) {
        for (int j = k >> 1; j >= 1; j >>= 1) {
            bool asc = ((t & (k >> 1)) == 0);
            if (j == 1) {
                if (act) {
                    bool sw = asc ? (v0 > v1) : (v0 < v1);
                    if (sw) { float tv = v0; v0 = v1; v1 = tv; int ti = id0; id0 = id1; id1 = ti; }
                }
            } else if (j <= 64) {
                if (act) {
                    int m = j >> 1;
                    float w0 = __shfl_xor(v0, m, 64);
                    int  wi0 = __shfl_xor(id0, m, 64);
                    float w1 = __shfl_xor(v1, m, 64);
                    int  wi1 = __shfl_xor(id1, m, 64);
                    bool low = ((t & m) == 0);
                    bool wantmin = (low == asc);
                    if (wantmin ? (w0 < v0) : (w0 > v0)) { v0 = w0; id0 = wi0; }
                    if (wantmin ? (w1 < v1) : (w1 > v1)) { v1 = w1; id1 = wi1; }
                }
            } else {
                int m = j >> 1;
                if (act) {
                    sA[2 * t] = v0; sA[2 * t + 1] = v1;
                    s_idxE[2 * t] = id0; s_idxE[2 * t + 1] = id1;
                }
                __syncthreads();
                if (act) {
                    int tp = t ^ m;
                    float w0 = sA[2 * tp], w1 = sA[2 * tp + 1];
                    int wi0 = s_idxE[2 * tp], wi1 = s_idxE[2 * tp + 1];
                    bool low = ((t & m) == 0);
                    bool wantmin = (low == asc);
                    if (wantmin ? (w0 < v0) : (w0 > v0)) { v0 = w0; id0 = wi0; }
                    if (wantmin ? (w1 < v1) : (w1 > v1)) { v1 = w1; id1 = wi1; }
                }
                __syncthreads();
            }
        }
    }

    if (act) { sA[2 * t] = v0; sA[2 * t + 1] = v1; }
    __syncthreads();
    const float M = sA[511];

    float e1_0 = 0.f, e1_1 = 0.f, e2_0 = 0.f, e2_1 = 0.f;
    if (act) {
        e1_0 = __expf(v0 - M);  e1_1 = __expf(v1 - M);
        e2_0 = __expf(0.2f * (v0 - M));  e2_1 = __expf(0.2f * (v1 - M));
        const int base = bh * 512;
        g_rE[base + id0] = make_float4(__int_as_float(2 * t),     e1_0, e2_0, 0.f);
        g_rE[base + id1] = make_float4(__int_as_float(2 * t + 1), e1_1, e2_1, 0.f);
    }

    float S1 = e1_0 + e1_1, S2 = e2_0 + e2_1;
    float i1 = S1, i2 = S2;
    if (act) {
        for (int off = 1; off < 64; off <<= 1) {
            float u1 = __shfl_up(i1, off, 64);
            float u2 = __shfl_up(i2, off, 64);
            if (lane >= off) { i1 += u1; i2 += u2; }
        }
        if (lane == 63) { wred[wid] = i1; wred[4 + wid] = i2; }
    }
    __syncthreads();
    if (act) {
        float off1 = 0.f, off2 = 0.f;
        for (int w = 0; w < wid; ++w) { off1 += wred[w]; off2 += wred[4 + w]; }
        const float T1 = wred[0] + wred[1] + wred[2] + wred[3];
        const float T2 = wred[4] + wred[5] + wred[6] + wred[7];
        float pre1 = off1 + i1 - S1;
        float pre2 = off2 + i2 - S2;
        z1suf[2 * t] = T1 - pre1;
        z1suf[2 * t + 1] = T1 - pre1 - e1_0;
        z2pre[2 * t] = pre2;
        z2pre[2 * t + 1] = pre2 + e2_0;
        if (t == 0) { z1suf[512] = 0.f; z2pre[512] = T2; }
    }
    __syncthreads();

    if (act) {
        for (int rr = 0; rr < 2; ++rr) {
            int i = t + rr * 256;
            float d = dreg[rr];
            int lo = 0, hi = 512;
            while (lo < hi) {
                int mid = (lo + hi) >> 1;
                if (d + sA[mid] >= 0.f) hi = mid; else lo = mid + 1;
            }
            int k = lo;
            float g = d + M;
            float G = (g >= 0.f) ? g : 0.2f * g;
            float al = __expf(g - G);
            float be = __expf(0.2f * g - G);
            float Z = al * z1suf[k] + be * z2pre[k];
            float inv = 1.0f / Z;
            g_abk[bh * 512 + i] = make_float4(al * inv, be * inv,
                                              __int_as_float(k), 0.f);
        }
    }
}

// ---------------------------------------------------------------------------
// Kernel B2: attn_agg_fin v9 (R30) — interleaved float2 LDS tables + fused
// per-(b,c) pooling output. XCD swizzle id%8==b%8 (R27), packed meta (R29).
// grid = 2048 blocks, 256 thr (4 waves = 4 heads).
// ---------------------------------------------------------------------------
__global__ __launch_bounds__(256) void attn_agg_fin(const float* __restrict__ hT,
                                                    const float4* __restrict__ g_rE,
                                                    const float4* __restrict__ g_abk,
                                                    const float* __restrict__ bias,
                                                    float* __restrict__ x,
                                                    float* __restrict__ pooled) {
    // R27 bijective swizzle: id%8 = b%8.
    const int r8 = blockIdx.x & 7;
    const int qq = blockIdx.x >> 3;
    const int cg = qq & 31;                // 0..31
    const int b  = ((qq >> 5) << 3) | r8;  // 0..63
    const int c0 = cg * 2;
    const int t = threadIdx.x;
    const int lane = t & 63, wv = t >> 6;  // wv = head 0..3

    __shared__ float2 A12[4][2][512];      // interleaved (A1,A2)
    __shared__ float tots[4][2];
    __shared__ float sredP[4][2];

    {
        const int bh = b * 4 + wv;
        const int base = bh * 512;
        const float* hTb = hT + (size_t)(wv * 64 + c0) * 32768 + (size_t)b * 512;
#pragma unroll
        for (int it = 0; it < 8; ++it) {
            int j = it * 64 + lane;
            float4 rE = g_rE[base + j];          // packed (rank, E1, E2)
            int rk = __float_as_int(rE.x);
            float h0 = hTb[j];
            float h1 = hTb[32768 + j];
            int pk = ((rk & 7) << 6) | (rk >> 3);
            A12[wv][0][pk] = make_float2(rE.y * h0, rE.z * h0);   // one b64
            A12[wv][1][pk] = make_float2(rE.y * h1, rE.z * h1);
        }
#pragma unroll
        for (int cc = 0; cc < 2; ++cc) {
            float v1[8], v2[8];
#pragma unroll
            for (int i = 0; i < 8; ++i) {
                float2 vv = A12[wv][cc][i * 64 + lane];           // one b64
                v1[i] = vv.x; v2[i] = vv.y;
            }
            float s1 = 0.f, s2 = 0.f;
#pragma unroll
            for (int i = 0; i < 8; ++i) { s1 += v1[i]; s2 += v2[i]; }
            float suf = s1;
#pragma unroll
            for (int off = 1; off < 64; off <<= 1) {
                float u = __shfl_down(suf, off, 64);
                if (lane + off < 64) suf += u;
            }
            float run = suf - s1;
            float pre = s2;
#pragma unroll
            for (int off = 1; off < 64; off <<= 1) {
                float u = __shfl_up(pre, off, 64);
                if (lane >= off) pre += u;
            }
            float run2 = pre - s2;
            if (lane == 63) tots[wv][cc] = pre;
#pragma unroll
            for (int i = 7; i >= 0; --i) { run += v1[i]; v1[i] = run; }
#pragma unroll
            for (int i = 0; i < 8; ++i) { float tv = v2[i]; v2[i] = run2; run2 += tv; }
#pragma unroll
            for (int i = 0; i < 8; ++i)
                A12[wv][cc][i * 64 + lane] = make_float2(v1[i], v2[i]);  // one b64
        }
    }
    __syncthreads();

    const float bv0 = bias[c0], bv1 = bias[c0 + 1];
    float p0 = 0.f, p1 = 0.f;              // per-thread pooled partials
#pragma unroll
    for (int rr = 0; rr < 2; ++rr) {
        const int i = t + rr * 256;
        float a0 = 0.f, a1 = 0.f;
#pragma unroll
        for (int head = 0; head < 4; ++head) {
            const int base = (b * 4 + head) * 512;
            float4 abk = g_abk[base + i];        // packed (aZ, bZ, k)
            int k = __float_as_int(abk.z);
            if (k < 512) {
                int pk = ((k & 7) << 6) | (k >> 3);
                float2 vv0 = A12[head][0][pk];   // one b64
                float2 vv1 = A12[head][1][pk];
                a0 += abk.x * vv0.x + abk.y * vv0.y;
                a1 += abk.x * vv1.x + abk.y * vv1.y;
            } else {
                a0 += abk.y * tots[head][0];
                a1 += abk.y * tots[head][1];
            }
        }
        float2 o = make_float2(fmaxf(0.25f * a0 + bv0, 0.f),
                               fmaxf(0.25f * a1 + bv1, 0.f));
        *(float2*)&x[(size_t)(b * 512 + i) * 64 + c0] = o;
        p0 += o.x; p1 += o.y;
    }

    // Fused pooling: this block exclusively owns (b, c0..c0+1) over all n.
#pragma unroll
    for (int m = 1; m <= 32; m <<= 1) {
        p0 += __shfl_xor(p0, m, 64);
        p1 += __shfl_xor(p1, m, 64);
    }
    if (lane == 0) { sredP[wv][0] = p0; sredP[wv][1] = p1; }
    __syncthreads();
    if (t == 0) {
        pooled[b * 64 + c0]     = sredP[0][0] + sredP[1][0] + sredP[2][0] + sredP[3][0];
        pooled[b * 64 + c0 + 1] = sredP[0][1] + sredP[1][1] + sredP[2][1] + sredP[3][1];
    }
}

// ---------------------------------------------------------------------------
// Kernel D: readout v2 — consumes 16KB pooled sums instead of 8MB xbuf.
// grid 64 x 64 threads.
// ---------------------------------------------------------------------------
__global__ __launch_bounds__(64) void readout_kernel(const float* __restrict__ pooled,
                                                     const float* __restrict__ rw,
                                                     const float* __restrict__ rb,
                                                     float* __restrict__ out) {
    __shared__ float pl[64];
    int b = blockIdx.x, t = threadIdx.x;
    pl[t] = pooled[b * 64 + t] * (1.0f / 512.0f);
    __syncthreads();
    float a = rb[t];
    for (int cc = 0; cc < 64; ++cc) a += pl[cc] * rw[t * 64 + cc];
    out[b * 64 + t] = a;
}

extern "C" void kernel_launch(void* const* d_in, const int* in_sizes, int n_in,
                              void* d_out, int out_size, void* d_ws, size_t ws_size,
                              hipStream_t stream) {
    const float* emb       = (const float*)d_in[0];
    const float* lin_w     = (const float*)d_in[1];
    const float* att_src   = (const float*)d_in[2];
    const float* att_dst   = (const float*)d_in[3];
    const float* conv_b    = (const float*)d_in[4];
    const float* readout_w = (const float*)d_in[5];
    const float* readout_b = (const float*)d_in[6];
    float* out = (float*)d_out;

    float* ws   = (float*)d_ws;
    float* xbuf = ws;                    // 8 MB
    float* hT   = ws + 2097152;          // 32 MB, [head][c][b*512+n]
    float* meta = ws + 10485760;         // 4 MB

    float4* g_rE   = (float4*)meta;                // [256*512] (rank,E1,E2,-)
    float4* g_abk  = (float4*)(meta + 524288);     // [256*512] (aZ,bZ,k,-)
    float*  pooled = ws + 11534336;                // [64*64] over-n sums

    for (int l = 0; l < 3; ++l) {
        const float* xin = (l == 0) ? emb : xbuf;
        linprep_kernel<<<256, 512, 0, stream>>>(xin, lin_w + (size_t)l * 16384,
                                                att_src + l * 256, att_dst + l * 256,
                                                hT, g_rE, g_abk);
        attn_agg_fin<<<2048, 256, 0, stream>>>(hT, g_rE, g_abk,
                                               conv_b + l * 64, xbuf, pooled);
    }
    readout_kernel<<<64, 64, 0, stream>>>(pooled, readout_w, readout_b, out);
}

// Round 15
// 197.453 us; speedup vs baseline: 1.4095x; 1.0199x over previous
//
#include <hip/hip_runtime.h>
#include <math.h>

// Problem constants (fixed by reference): B=64, N=512, D=64, H=4, C=64, L=3
// Workspace layout (floats), ws >= 256 MB:
//   xbuf [0 .. 2097152)          : layer activations x (8 MB)
//   hT   [2097152 .. 10485760)   : h TRANSPOSED [head][c][b*512+n] (32 MB)
//   meta [10485760 .. 11534336)  : g_rE float4 + g_abk float4 (4 MB)
//   pooled [11534336 .. +4096)   : per-(b,c) over-n sums (16 KB)
// History: R23 237.2 -> R27 235.9 -> R28 231.6 -> R29 229.2 -> R30 201.4
// BEST (A12 float2 interleave + fused pooling; -27.8us — LDS message count
// was agg's dominant cost; mechanism now 3-for-3 and super-linear on LDS
// critical path). absmax improved to 1.9e-06 (tree pooling).
// R31 (this): same mechanism, one level further:
//   a) A12 -> float4[4][512] {A1c0,A2c0,A1c1,A2c1}: fill scatter 2xb64 ->
//      1xb128, scan IO 2xb64 -> 1xb128, query 2 random b64 -> 1 random
//      b128. Halves agg LDS messages AGAIN. Per-plane fp32 op order
//      identical -> bit-identical.
//   b) storex flag: layer-3 xbuf store skipped (consumed only via pooled)
//      -> 8 MB dead writes removed.
// Decision rule: >=201.4 -> revert to exact R30.

using short8  = __attribute__((ext_vector_type(8))) short;
using floatx4 = __attribute__((ext_vector_type(4))) float;

__device__ inline unsigned short f2bf(float f) {
    union { float f; unsigned u; } v; v.f = f;
    unsigned u = v.u + 0x7FFFu + ((v.u >> 16) & 1u);   // round-to-nearest-even
    return (unsigned short)(u >> 16);
}
__device__ inline float bf2f(unsigned short s) {
    union { float f; unsigned u; } v; v.u = ((unsigned)s) << 16;
    return v.f;
}

// 8 floats (two float4) -> split-bf16 hi/lo short8 fragments, in registers.
__device__ inline void cvt8(const float4 a, const float4 b, short8& hi, short8& lo) {
    float f[8] = {a.x, a.y, a.z, a.w, b.x, b.y, b.z, b.w};
    short8 H, L;
#pragma unroll
    for (int i = 0; i < 8; ++i) {
        unsigned short h = f2bf(f[i]);
        H[i] = (short)h;
        L[i] = (short)f2bf(f[i] - bf2f(h));
    }
    hi = H; lo = L;
}

// ---------------------------------------------------------------------------
// Kernel A+B1 fused: linprep v4 (R29, UNCHANGED) — 512 threads, grid 256,
// XCD swizzle id%8==b%8, prep on t<256 with unconditional barriers.
// ---------------------------------------------------------------------------
__global__ __launch_bounds__(512) void linprep_kernel(const float* __restrict__ x,
                                                      const float* __restrict__ W,
                                                      const float* __restrict__ att_src,
                                                      const float* __restrict__ att_dst,
                                                      float* __restrict__ hT,
                                                      float4* __restrict__ g_rE,
                                                      float4* __restrict__ g_abk) {
    __shared__ unsigned short WH[64 * 72], WL[64 * 72];
    __shared__ float sA[512], dA[512];      // s/d dots (then sA sorted in place)
    __shared__ int   s_idxE[512];
    __shared__ float z1suf[513], z2pre[513];
    __shared__ float wred[8];

    const int t  = threadIdx.x;
    // R28 bijective swizzle: id%8 = b%8 (4 head-blocks of b on one XCD).
    const int r8 = blockIdx.x & 7;
    const int q  = blockIdx.x >> 3;       // 0..31
    const int ct = q & 3;                 // head
    const int b  = ((q >> 2) << 3) | r8;  // 0..63
    const int bh = b * 4 + ct;            // meta layout index (unchanged)
    const int c0 = ct * 64;

    // ---- W staging + convert, ONCE per block (512 thr: 2 float4 each) ----
#pragma unroll
    for (int qq = 0; qq < 2; ++qq) {
        int f = qq * 512 + t;
        int wrow = f >> 4, d4 = f & 15;
        float4 v = *(const float4*)(W + (size_t)(c0 + wrow) * 64 + d4 * 4);
        unsigned short h0 = f2bf(v.x), h1 = f2bf(v.y), h2 = f2bf(v.z), h3 = f2bf(v.w);
        ushort4 hi = make_ushort4(h0, h1, h2, h3);
        ushort4 lo = make_ushort4(f2bf(v.x - bf2f(h0)), f2bf(v.y - bf2f(h1)),
                                  f2bf(v.z - bf2f(h2)), f2bf(v.w - bf2f(h3)));
        *(ushort4*)&WH[wrow * 72 + d4 * 4] = hi;
        *(ushort4*)&WL[wrow * 72 + d4 * 4] = lo;
    }
    __syncthreads();

    const int lane = t & 63, wv = t >> 6;   // wv = 0..7
    const int mrow = lane & 15, quad = lane >> 4;

    // ---- per-wave W fragments for ALL 4 channel groups (REGISTERS) ----
    short8 bhf[4][2], blf[4][2];
#pragma unroll
    for (int g = 0; g < 4; ++g)
#pragma unroll
        for (int kk = 0; kk < 2; ++kk) {
            int ko = kk * 32 + quad * 8;
            bhf[g][kk] = *(const short8*)&WH[(g * 16 + mrow) * 72 + ko];
            blf[g][kk] = *(const short8*)&WL[(g * 16 + mrow) * 72 + ko];
        }
    float as_g[4], ad_g[4];
#pragma unroll
    for (int g = 0; g < 4; ++g) {
        as_g[g] = att_src[c0 + g * 16 + mrow];
        ad_g[g] = att_dst[c0 + g * 16 + mrow];
    }

    // ---- lin: wave wv owns tiles wv, wv+8, wv+16, wv+24 (1-deep prefetch) --
    const float* xbase = x + (size_t)(b * 512 + mrow) * 64 + quad * 8;
    float4 nxa = *(const float4*)(xbase + (size_t)wv * 1024);
    float4 nxb = *(const float4*)(xbase + (size_t)wv * 1024 + 4);
    float4 nxc = *(const float4*)(xbase + (size_t)wv * 1024 + 32);
    float4 nxd = *(const float4*)(xbase + (size_t)wv * 1024 + 36);

#pragma unroll 1
    for (int tl = wv; tl < 32; tl += 8) {
        float4 xa = nxa, xb = nxb, xc = nxc, xd = nxd;
        if (tl + 8 < 32) {
            const float* nb = xbase + (size_t)(tl + 8) * 1024;
            nxa = *(const float4*)(nb);
            nxb = *(const float4*)(nb + 4);
            nxc = *(const float4*)(nb + 32);
            nxd = *(const float4*)(nb + 36);
        }
        short8 ah0, al0, ah1, al1;
        cvt8(xa, xb, ah0, al0);
        cvt8(xc, xd, ah1, al1);

        floatx4 acc[4];
#pragma unroll
        for (int g = 0; g < 4; ++g) {
            floatx4 a = {0.f, 0.f, 0.f, 0.f};
            a = __builtin_amdgcn_mfma_f32_16x16x32_bf16(ah0, bhf[g][0], a, 0, 0, 0);
            a = __builtin_amdgcn_mfma_f32_16x16x32_bf16(ah1, bhf[g][1], a, 0, 0, 0);
            a = __builtin_amdgcn_mfma_f32_16x16x32_bf16(ah0, blf[g][0], a, 0, 0, 0);
            a = __builtin_amdgcn_mfma_f32_16x16x32_bf16(ah1, blf[g][1], a, 0, 0, 0);
            a = __builtin_amdgcn_mfma_f32_16x16x32_bf16(al0, bhf[g][0], a, 0, 0, 0);
            a = __builtin_amdgcn_mfma_f32_16x16x32_bf16(al1, bhf[g][1], a, 0, 0, 0);
            acc[g] = a;
        }

        const int r0 = b * 512 + tl * 16;
#pragma unroll
        for (int g = 0; g < 4; ++g) {
            *(float4*)&hT[(size_t)(ct * 64 + g * 16 + mrow) * 32768 + r0 + quad * 4] =
                make_float4(acc[g][0], acc[g][1], acc[g][2], acc[g][3]);
        }

        float ps[4], pd[4];
#pragma unroll
        for (int reg = 0; reg < 4; ++reg) {
            ps[reg] = acc[0][reg] * as_g[0] + acc[1][reg] * as_g[1]
                    + acc[2][reg] * as_g[2] + acc[3][reg] * as_g[3];
            pd[reg] = acc[0][reg] * ad_g[0] + acc[1][reg] * ad_g[1]
                    + acc[2][reg] * ad_g[2] + acc[3][reg] * ad_g[3];
        }
#pragma unroll
        for (int m = 1; m <= 8; m <<= 1) {
#pragma unroll
            for (int reg = 0; reg < 4; ++reg) {
                ps[reg] += __shfl_xor(ps[reg], m, 64);
                pd[reg] += __shfl_xor(pd[reg], m, 64);
            }
        }
        if (mrow < 4) {
            sA[tl * 16 + quad * 4 + mrow] = ps[mrow];
            dA[tl * 16 + quad * 4 + mrow] = pd[mrow];
        }
    }
    __syncthreads();

    // ======================= prep body: t<256 active ========================
    const bool act = (t < 256);
    const int wid = t >> 6;               // 0..3 when act

    float dreg[2] = {0.f, 0.f};
    if (act) {
        dreg[0] = dA[t];
        dreg[1] = dA[t + 256];
    }

    float v0 = 0.f, v1 = 0.f;
    int id0 = 0, id1 = 0;
    if (act) { v0 = sA[2 * t]; v1 = sA[2 * t + 1]; id0 = 2 * t; id1 = 2 * t + 1; }

    for (int k = 2; k <= 512; k <<= 1) {
        for (int j = k >> 1; j >= 1; j >>= 1) {
            bool asc = ((t & (k >> 1)) == 0);
            if (j == 1) {
                if (act) {
                    bool sw = asc ? (v0 > v1) : (v0 < v1);
                    if (sw) { float tv = v0; v0 = v1; v1 = tv; int ti = id0; id0 = id1; id1 = ti; }
                }
            } else if (j <= 64) {
                if (act) {
                    int m = j >> 1;
                    float w0 = __shfl_xor(v0, m, 64);
                    int  wi0 = __shfl_xor(id0, m, 64);
                    float w1 = __shfl_xor(v1, m, 64);
                    int  wi1 = __shfl_xor(id1, m, 64);
                    bool low = ((t & m) == 0);
                    bool wantmin = (low == asc);
                    if (wantmin ? (w0 < v0) : (w0 > v0)) { v0 = w0; id0 = wi0; }
                    if (wantmin ? (w1 < v1) : (w1 > v1)) { v1 = w1; id1 = wi1; }
                }
            } else {
                int m = j >> 1;
                if (act) {
                    sA[2 * t] = v0; sA[2 * t + 1] = v1;
                    s_idxE[2 * t] = id0; s_idxE[2 * t + 1] = id1;
                }
                __syncthreads();
                if (act) {
                    int tp = t ^ m;
                    float w0 = sA[2 * tp], w1 = sA[2 * tp + 1];
                    int wi0 = s_idxE[2 * tp], wi1 = s_idxE[2 * tp + 1];
                    bool low = ((t & m) == 0);
                    bool wantmin = (low == asc);
                    if (wantmin ? (w0 < v0) : (w0 > v0)) { v0 = w0; id0 = wi0; }
                    if (wantmin ? (w1 < v1) : (w1 > v1)) { v1 = w1; id1 = wi1; }
                }
                __syncthreads();
            }
        }
    }

    if (act) { sA[2 * t] = v0; sA[2 * t + 1] = v1; }
    __syncthreads();
    const float M = sA[511];

    float e1_0 = 0.f, e1_1 = 0.f, e2_0 = 0.f, e2_1 = 0.f;
    if (act) {
        e1_0 = __expf(v0 - M);  e1_1 = __expf(v1 - M);
        e2_0 = __expf(0.2f * (v0 - M));  e2_1 = __expf(0.2f * (v1 - M));
        const int base = bh * 512;
        g_rE[base + id0] = make_float4(__int_as_float(2 * t),     e1_0, e2_0, 0.f);
        g_rE[base + id1] = make_float4(__int_as_float(2 * t + 1), e1_1, e2_1, 0.f);
    }

    float S1 = e1_0 + e1_1, S2 = e2_0 + e2_1;
    float i1 = S1, i2 = S2;
    if (act) {
        for (int off = 1; off < 64; off <<= 1) {
            float u1 = __shfl_up(i1, off, 64);
            float u2 = __shfl_up(i2, off, 64);
            if (lane >= off) { i1 += u1; i2 += u2; }
        }
        if (lane == 63) { wred[wid] = i1; wred[4 + wid] = i2; }
    }
    __syncthreads();
    if (act) {
        float off1 = 0.f, off2 = 0.f;
        for (int w = 0; w < wid; ++w) { off1 += wred[w]; off2 += wred[4 + w]; }
        const float T1 = wred[0] + wred[1] + wred[2] + wred[3];
        const float T2 = wred[4] + wred[5] + wred[6] + wred[7];
        float pre1 = off1 + i1 - S1;
        float pre2 = off2 + i2 - S2;
        z1suf[2 * t] = T1 - pre1;
        z1suf[2 * t + 1] = T1 - pre1 - e1_0;
        z2pre[2 * t] = pre2;
        z2pre[2 * t + 1] = pre2 + e2_0;
        if (t == 0) { z1suf[512] = 0.f; z2pre[512] = T2; }
    }
    __syncthreads();

    if (act) {
        for (int rr = 0; rr < 2; ++rr) {
            int i = t + rr * 256;
            float d = dreg[rr];
            int lo = 0, hi = 512;
            while (lo < hi) {
                int mid = (lo + hi) >> 1;
                if (d + sA[mid] >= 0.f) hi = mid; else lo = mid + 1;
            }
            int k = lo;
            float g = d + M;
            float G = (g >= 0.f) ? g : 0.2f * g;
            float al = __expf(g - G);
            float be = __expf(0.2f * g - G);
            float Z = al * z1suf[k] + be * z2pre[k];
            float inv = 1.0f / Z;
            g_abk[bh * 512 + i] = make_float4(al * inv, be * inv,
                                              __int_as_float(k), 0.f);
        }
    }
}

// ---------------------------------------------------------------------------
// Kernel B2: attn_agg_fin v10 (R31) — float4 LDS tables (both channels
// interleaved) + fused pooling + optional x store. XCD swizzle (R27),
// packed meta (R29). grid = 2048 blocks, 256 thr (4 waves = 4 heads).
// ---------------------------------------------------------------------------
__global__ __launch_bounds__(256) void attn_agg_fin(const float* __restrict__ hT,
                                                    const float4* __restrict__ g_rE,
                                                    const float4* __restrict__ g_abk,
                                                    const float* __restrict__ bias,
                                                    float* __restrict__ x,
                                                    float* __restrict__ pooled,
                                                    int storex) {
    // R27 bijective swizzle: id%8 = b%8.
    const int r8 = blockIdx.x & 7;
    const int qq = blockIdx.x >> 3;
    const int cg = qq & 31;                // 0..31
    const int b  = ((qq >> 5) << 3) | r8;  // 0..63
    const int c0 = cg * 2;
    const int t = threadIdx.x;
    const int lane = t & 63, wv = t >> 6;  // wv = head 0..3

    __shared__ float4 A12[4][512];         // {A1c0, A2c0, A1c1, A2c1}
    __shared__ float tots[4][2];
    __shared__ float sredP[4][2];

    {
        const int bh = b * 4 + wv;
        const int base = bh * 512;
        const float* hTb = hT + (size_t)(wv * 64 + c0) * 32768 + (size_t)b * 512;
#pragma unroll
        for (int it = 0; it < 8; ++it) {
            int j = it * 64 + lane;
            float4 rE = g_rE[base + j];          // packed (rank, E1, E2)
            int rk = __float_as_int(rE.x);
            float h0 = hTb[j];
            float h1 = hTb[32768 + j];
            int pk = ((rk & 7) << 6) | (rk >> 3);
            A12[wv][pk] = make_float4(rE.y * h0, rE.z * h0,
                                      rE.y * h1, rE.z * h1);   // one b128
        }
        // scan: all four planes in one pass (per-plane op order = R30)
        float a1c0[8], a2c0[8], a1c1[8], a2c1[8];
#pragma unroll
        for (int i = 0; i < 8; ++i) {
            float4 vv = A12[wv][i * 64 + lane];                // one b128
            a1c0[i] = vv.x; a2c0[i] = vv.y; a1c1[i] = vv.z; a2c1[i] = vv.w;
        }
        float s10 = 0.f, s20 = 0.f, s11 = 0.f, s21 = 0.f;
#pragma unroll
        for (int i = 0; i < 8; ++i) {
            s10 += a1c0[i]; s20 += a2c0[i]; s11 += a1c1[i]; s21 += a2c1[i];
        }
        float suf0 = s10, suf1 = s11;
#pragma unroll
        for (int off = 1; off < 64; off <<= 1) {
            float u0 = __shfl_down(suf0, off, 64);
            float u1 = __shfl_down(suf1, off, 64);
            if (lane + off < 64) { suf0 += u0; suf1 += u1; }
        }
        float run0 = suf0 - s10, run1 = suf1 - s11;      // exclusive suffix
        float pre0 = s20, pre1 = s21;
#pragma unroll
        for (int off = 1; off < 64; off <<= 1) {
            float u0 = __shfl_up(pre0, off, 64);
            float u1 = __shfl_up(pre1, off, 64);
            if (lane >= off) { pre0 += u0; pre1 += u1; }
        }
        float run20 = pre0 - s20, run21 = pre1 - s21;    // exclusive prefix
        if (lane == 63) { tots[wv][0] = pre0; tots[wv][1] = pre1; }
#pragma unroll
        for (int i = 7; i >= 0; --i) {
            run0 += a1c0[i]; a1c0[i] = run0;             // incl suffix
            run1 += a1c1[i]; a1c1[i] = run1;
        }
#pragma unroll
        for (int i = 0; i < 8; ++i) {
            float tv0 = a2c0[i]; a2c0[i] = run20; run20 += tv0;  // excl prefix
            float tv1 = a2c1[i]; a2c1[i] = run21; run21 += tv1;
        }
#pragma unroll
        for (int i = 0; i < 8; ++i)
            A12[wv][i * 64 + lane] = make_float4(a1c0[i], a2c0[i],
                                                 a1c1[i], a2c1[i]);  // one b128
    }
    __syncthreads();

    const float bv0 = bias[c0], bv1 = bias[c0 + 1];
    float p0 = 0.f, p1 = 0.f;              // per-thread pooled partials
#pragma unroll
    for (int rr = 0; rr < 2; ++rr) {
        const int i = t + rr * 256;
        float a0 = 0.f, a1 = 0.f;
#pragma unroll
        for (int head = 0; head < 4; ++head) {
            const int base = (b * 4 + head) * 512;
            float4 abk = g_abk[base + i];        // packed (aZ, bZ, k)
            int k = __float_as_int(abk.z);
            if (k < 512) {
                int pk = ((k & 7) << 6) | (k >> 3);
                float4 vv = A12[head][pk];       // one random b128
                a0 += abk.x * vv.x + abk.y * vv.y;
                a1 += abk.x * vv.z + abk.y * vv.w;
            } else {
                a0 += abk.y * tots[head][0];
                a1 += abk.y * tots[head][1];
            }
        }
        float2 o = make_float2(fmaxf(0.25f * a0 + bv0, 0.f),
                               fmaxf(0.25f * a1 + bv1, 0.f));
        if (storex) *(float2*)&x[(size_t)(b * 512 + i) * 64 + c0] = o;
        p0 += o.x; p1 += o.y;
    }

    // Fused pooling: this block exclusively owns (b, c0..c0+1) over all n.
#pragma unroll
    for (int m = 1; m <= 32; m <<= 1) {
        p0 += __shfl_xor(p0, m, 64);
        p1 += __shfl_xor(p1, m, 64);
    }
    if (lane == 0) { sredP[wv][0] = p0; sredP[wv][1] = p1; }
    __syncthreads();
    if (t == 0) {
        pooled[b * 64 + c0]     = sredP[0][0] + sredP[1][0] + sredP[2][0] + sredP[3][0];
        pooled[b * 64 + c0 + 1] = sredP[0][1] + sredP[1][1] + sredP[2][1] + sredP[3][1];
    }
}

// ---------------------------------------------------------------------------
// Kernel D: readout v2 — consumes 16KB pooled sums. grid 64 x 64 threads.
// ---------------------------------------------------------------------------
__global__ __launch_bounds__(64) void readout_kernel(const float* __restrict__ pooled,
                                                     const float* __restrict__ rw,
                                                     const float* __restrict__ rb,
                                                     float* __restrict__ out) {
    __shared__ float pl[64];
    int b = blockIdx.x, t = threadIdx.x;
    pl[t] = pooled[b * 64 + t] * (1.0f / 512.0f);
    __syncthreads();
    float a = rb[t];
    for (int cc = 0; cc < 64; ++cc) a += pl[cc] * rw[t * 64 + cc];
    out[b * 64 + t] = a;
}

extern "C" void kernel_launch(void* const* d_in, const int* in_sizes, int n_in,
                              void* d_out, int out_size, void* d_ws, size_t ws_size,
                              hipStream_t stream) {
    const float* emb       = (const float*)d_in[0];
    const float* lin_w     = (const float*)d_in[1];
    const float* att_src   = (const float*)d_in[2];
    const float* att_dst   = (const float*)d_in[3];
    const float* conv_b    = (const float*)d_in[4];
    const float* readout_w = (const float*)d_in[5];
    const float* readout_b = (const float*)d_in[6];
    float* out = (float*)d_out;

    float* ws   = (float*)d_ws;
    float* xbuf = ws;                    // 8 MB
    float* hT   = ws + 2097152;          // 32 MB, [head][c][b*512+n]
    float* meta = ws + 10485760;         // 4 MB

    float4* g_rE   = (float4*)meta;                // [256*512] (rank,E1,E2,-)
    float4* g_abk  = (float4*)(meta + 524288);     // [256*512] (aZ,bZ,k,-)
    float*  pooled = ws + 11534336;                // [64*64] over-n sums

    for (int l = 0; l < 3; ++l) {
        const float* xin = (l == 0) ? emb : xbuf;
        linprep_kernel<<<256, 512, 0, stream>>>(xin, lin_w + (size_t)l * 16384,
                                                att_src + l * 256, att_dst + l * 256,
                                                hT, g_rE, g_abk);
        attn_agg_fin<<<2048, 256, 0, stream>>>(hT, g_rE, g_abk,
                                               conv_b + l * 64, xbuf, pooled,
                                               (l < 2) ? 1 : 0);
    }
    readout_kernel<<<64, 64, 0, stream>>>(pooled, readout_w, readout_b, out);
}

// Round 16
// 196.112 us; speedup vs baseline: 1.4191x; 1.0068x over previous
//
#include <hip/hip_runtime.h>
#include <math.h>

// Problem constants (fixed by reference): B=64, N=512, D=64, H=4, C=64, L=3
// Workspace layout (floats), ws >= 256 MB:
//   xbuf [0 .. 2097152)          : layer activations x (8 MB)
//   hT   [2097152 .. 10485760)   : h channel-pair interleaved (R32):
//                                  [head*32+cp][(b*512+n)*2 + parity] (32 MB)
//   meta [10485760 .. 11534336)  : g_rE float4 + g_abk float4 (4 MB)
//   pooled [11534336 .. +4096)   : per-(b,c) over-n sums (16 KB)
// History: R23 237.2 -> R27 235.9 -> R28 231.6 -> R29 229.2 -> R30 201.4
// -> R31 197.5 BEST (float4 LDS tables + storex skip). Message-count
// reduction mechanism now 4-for-4 (super-linear when on LDS critical path).
// R32 (this): same mechanism on the hT producer->consumer stream:
//   hT re-laid channel-pair interleaved. agg fill reads ONE float2 per j
//   (was 2 loads 128KB apart); linprep stores via lane-pair shfl_xor(1)
//   exchange (4 shuffles/g), store coalescing improves 16x64B -> 8x128B
//   segments per wave-instruction. Same values in every slot -> bit-identical
//   (absmax must stay 1.907349e-06).
// Decision rule: >=197.5 -> revert to exact R31, declare ~197 the floor.

using short8  = __attribute__((ext_vector_type(8))) short;
using floatx4 = __attribute__((ext_vector_type(4))) float;

__device__ inline unsigned short f2bf(float f) {
    union { float f; unsigned u; } v; v.f = f;
    unsigned u = v.u + 0x7FFFu + ((v.u >> 16) & 1u);   // round-to-nearest-even
    return (unsigned short)(u >> 16);
}
__device__ inline float bf2f(unsigned short s) {
    union { float f; unsigned u; } v; v.u = ((unsigned)s) << 16;
    return v.f;
}

// 8 floats (two float4) -> split-bf16 hi/lo short8 fragments, in registers.
__device__ inline void cvt8(const float4 a, const float4 b, short8& hi, short8& lo) {
    float f[8] = {a.x, a.y, a.z, a.w, b.x, b.y, b.z, b.w};
    short8 H, L;
#pragma unroll
    for (int i = 0; i < 8; ++i) {
        unsigned short h = f2bf(f[i]);
        H[i] = (short)h;
        L[i] = (short)f2bf(f[i] - bf2f(h));
    }
    hi = H; lo = L;
}

// ---------------------------------------------------------------------------
// Kernel A+B1 fused: linprep v5 (R32) — R29 body + channel-pair hT stores.
// 512 threads, grid 256, XCD swizzle id%8==b%8, prep on t<256.
// ---------------------------------------------------------------------------
__global__ __launch_bounds__(512) void linprep_kernel(const float* __restrict__ x,
                                                      const float* __restrict__ W,
                                                      const float* __restrict__ att_src,
                                                      const float* __restrict__ att_dst,
                                                      float* __restrict__ hT,
                                                      float4* __restrict__ g_rE,
                                                      float4* __restrict__ g_abk) {
    __shared__ unsigned short WH[64 * 72], WL[64 * 72];
    __shared__ float sA[512], dA[512];      // s/d dots (then sA sorted in place)
    __shared__ int   s_idxE[512];
    __shared__ float z1suf[513], z2pre[513];
    __shared__ float wred[8];

    const int t  = threadIdx.x;
    // R28 bijective swizzle: id%8 = b%8 (4 head-blocks of b on one XCD).
    const int r8 = blockIdx.x & 7;
    const int q  = blockIdx.x >> 3;       // 0..31
    const int ct = q & 3;                 // head
    const int b  = ((q >> 2) << 3) | r8;  // 0..63
    const int bh = b * 4 + ct;            // meta layout index (unchanged)
    const int c0 = ct * 64;

    // ---- W staging + convert, ONCE per block (512 thr: 2 float4 each) ----
#pragma unroll
    for (int qq = 0; qq < 2; ++qq) {
        int f = qq * 512 + t;
        int wrow = f >> 4, d4 = f & 15;
        float4 v = *(const float4*)(W + (size_t)(c0 + wrow) * 64 + d4 * 4);
        unsigned short h0 = f2bf(v.x), h1 = f2bf(v.y), h2 = f2bf(v.z), h3 = f2bf(v.w);
        ushort4 hi = make_ushort4(h0, h1, h2, h3);
        ushort4 lo = make_ushort4(f2bf(v.x - bf2f(h0)), f2bf(v.y - bf2f(h1)),
                                  f2bf(v.z - bf2f(h2)), f2bf(v.w - bf2f(h3)));
        *(ushort4*)&WH[wrow * 72 + d4 * 4] = hi;
        *(ushort4*)&WL[wrow * 72 + d4 * 4] = lo;
    }
    __syncthreads();

    const int lane = t & 63, wv = t >> 6;   // wv = 0..7
    const int mrow = lane & 15, quad = lane >> 4;

    // ---- per-wave W fragments for ALL 4 channel groups (REGISTERS) ----
    short8 bhf[4][2], blf[4][2];
#pragma unroll
    for (int g = 0; g < 4; ++g)
#pragma unroll
        for (int kk = 0; kk < 2; ++kk) {
            int ko = kk * 32 + quad * 8;
            bhf[g][kk] = *(const short8*)&WH[(g * 16 + mrow) * 72 + ko];
            blf[g][kk] = *(const short8*)&WL[(g * 16 + mrow) * 72 + ko];
        }
    float as_g[4], ad_g[4];
#pragma unroll
    for (int g = 0; g < 4; ++g) {
        as_g[g] = att_src[c0 + g * 16 + mrow];
        ad_g[g] = att_dst[c0 + g * 16 + mrow];
    }

    // ---- lin: wave wv owns tiles wv, wv+8, wv+16, wv+24 (1-deep prefetch) --
    const float* xbase = x + (size_t)(b * 512 + mrow) * 64 + quad * 8;
    float4 nxa = *(const float4*)(xbase + (size_t)wv * 1024);
    float4 nxb = *(const float4*)(xbase + (size_t)wv * 1024 + 4);
    float4 nxc = *(const float4*)(xbase + (size_t)wv * 1024 + 32);
    float4 nxd = *(const float4*)(xbase + (size_t)wv * 1024 + 36);

#pragma unroll 1
    for (int tl = wv; tl < 32; tl += 8) {
        float4 xa = nxa, xb = nxb, xc = nxc, xd = nxd;
        if (tl + 8 < 32) {
            const float* nb = xbase + (size_t)(tl + 8) * 1024;
            nxa = *(const float4*)(nb);
            nxb = *(const float4*)(nb + 4);
            nxc = *(const float4*)(nb + 32);
            nxd = *(const float4*)(nb + 36);
        }
        short8 ah0, al0, ah1, al1;
        cvt8(xa, xb, ah0, al0);
        cvt8(xc, xd, ah1, al1);

        floatx4 acc[4];
#pragma unroll
        for (int g = 0; g < 4; ++g) {
            floatx4 a = {0.f, 0.f, 0.f, 0.f};
            a = __builtin_amdgcn_mfma_f32_16x16x32_bf16(ah0, bhf[g][0], a, 0, 0, 0);
            a = __builtin_amdgcn_mfma_f32_16x16x32_bf16(ah1, bhf[g][1], a, 0, 0, 0);
            a = __builtin_amdgcn_mfma_f32_16x16x32_bf16(ah0, blf[g][0], a, 0, 0, 0);
            a = __builtin_amdgcn_mfma_f32_16x16x32_bf16(ah1, blf[g][1], a, 0, 0, 0);
            a = __builtin_amdgcn_mfma_f32_16x16x32_bf16(al0, bhf[g][0], a, 0, 0, 0);
            a = __builtin_amdgcn_mfma_f32_16x16x32_bf16(al1, bhf[g][1], a, 0, 0, 0);
            acc[g] = a;
        }

        // ---- R32: channel-pair interleaved hT store via lane-pair exchange.
        // hT2[(ct*32 + g*8 + mrow>>1)*65536 + (b*512 + n)*2 + (mrow&1)]
        // even lane stores n0..n1 {e0,o0,e1,o1}; odd lane n2..n3 {e2,o2,e3,o3}.
        const int nbase = b * 512 + tl * 16 + quad * 4;
#pragma unroll
        for (int g = 0; g < 4; ++g) {
            float tmp0 = __shfl_xor(acc[g][0], 1, 64);
            float tmp1 = __shfl_xor(acc[g][1], 1, 64);
            float tmp2 = __shfl_xor(acc[g][2], 1, 64);
            float tmp3 = __shfl_xor(acc[g][3], 1, 64);
            const size_t cp = (size_t)(ct * 32 + g * 8 + (mrow >> 1));
            if ((mrow & 1) == 0) {
                *(float4*)&hT[cp * 65536 + (size_t)nbase * 2] =
                    make_float4(acc[g][0], tmp0, acc[g][1], tmp1);
            } else {
                *(float4*)&hT[cp * 65536 + (size_t)(nbase + 2) * 2] =
                    make_float4(tmp2, acc[g][2], tmp3, acc[g][3]);
            }
        }

        float ps[4], pd[4];
#pragma unroll
        for (int reg = 0; reg < 4; ++reg) {
            ps[reg] = acc[0][reg] * as_g[0] + acc[1][reg] * as_g[1]
                    + acc[2][reg] * as_g[2] + acc[3][reg] * as_g[3];
            pd[reg] = acc[0][reg] * ad_g[0] + acc[1][reg] * ad_g[1]
                    + acc[2][reg] * ad_g[2] + acc[3][reg] * ad_g[3];
        }
#pragma unroll
        for (int m = 1; m <= 8; m <<= 1) {
#pragma unroll
            for (int reg = 0; reg < 4; ++reg) {
                ps[reg] += __shfl_xor(ps[reg], m, 64);
                pd[reg] += __shfl_xor(pd[reg], m, 64);
            }
        }
        if (mrow < 4) {
            sA[tl * 16 + quad * 4 + mrow] = ps[mrow];
            dA[tl * 16 + quad * 4 + mrow] = pd[mrow];
        }
    }
    __syncthreads();

    // ======================= prep body: t<256 active ========================
    const bool act = (t < 256);
    const int wid = t >> 6;               // 0..3 when act

    float dreg[2] = {0.f, 0.f};
    if (act) {
        dreg[0] = dA[t];
        dreg[1] = dA[t + 256];
    }

    float v0 = 0.f, v1 = 0.f;
    int id0 = 0, id1 = 0;
    if (act) { v0 = sA[2 * t]; v1 = sA[2 * t + 1]; id0 = 2 * t; id1 = 2 * t + 1; }

    for (int k = 2; k <= 512; k <<= 1) {
        for (int j = k >> 1; j >= 1; j >>= 1) {
            bool asc = ((t & (k >> 1)) == 0);
            if (j == 1) {
                if (act) {
                    bool sw = asc ? (v0 > v1) : (v0 < v1);
                    if (sw) { float tv = v0; v0 = v1; v1 = tv; int ti = id0; id0 = id1; id1 = ti; }
                }
            } else if (j <= 64) {
                if (act) {
                    int m = j >> 1;
                    float w0 = __shfl_xor(v0, m, 64);
                    int  wi0 = __shfl_xor(id0, m, 64);
                    float w1 = __shfl_xor(v1, m, 64);
                    int  wi1 = __shfl_xor(id1, m, 64);
                    bool low = ((t & m) == 0);
                    bool wantmin = (low == asc);
                    if (wantmin ? (w0 < v0) : (w0 > v0)) { v0 = w0; id0 = wi0; }
                    if (wantmin ? (w1 < v1) : (w1 > v1)) { v1 = w1; id1 = wi1; }
                }
            } else {
                int m = j >> 1;
                if (act) {
                    sA[2 * t] = v0; sA[2 * t + 1] = v1;
                    s_idxE[2 * t] = id0; s_idxE[2 * t + 1] = id1;
                }
                __syncthreads();
                if (act) {
                    int tp = t ^ m;
                    float w0 = sA[2 * tp], w1 = sA[2 * tp + 1];
                    int wi0 = s_idxE[2 * tp], wi1 = s_idxE[2 * tp + 1];
                    bool low = ((t & m) == 0);
                    bool wantmin = (low == asc);
                    if (wantmin ? (w0 < v0) : (w0 > v0)) { v0 = w0; id0 = wi0; }
                    if (wantmin ? (w1 < v1) : (w1 > v1)) { v1 = w1; id1 = wi1; }
                }
                __syncthreads();
            }
        }
    }

    if (act) { sA[2 * t] = v0; sA[2 * t + 1] = v1; }
    __syncthreads();
    const float M = sA[511];

    float e1_0 = 0.f, e1_1 = 0.f, e2_0 = 0.f, e2_1 = 0.f;
    if (act) {
        e1_0 = __expf(v0 - M);  e1_1 = __expf(v1 - M);
        e2_0 = __expf(0.2f * (v0 - M));  e2_1 = __expf(0.2f * (v1 - M));
        const int base = bh * 512;
        g_rE[base + id0] = make_float4(__int_as_float(2 * t),     e1_0, e2_0, 0.f);
        g_rE[base + id1] = make_float4(__int_as_float(2 * t + 1), e1_1, e2_1, 0.f);
    }

    float S1 = e1_0 + e1_1, S2 = e2_0 + e2_1;
    float i1 = S1, i2 = S2;
    if (act) {
        for (int off = 1; off < 64; off <<= 1) {
            float u1 = __shfl_up(i1, off, 64);
            float u2 = __shfl_up(i2, off, 64);
            if (lane >= off) { i1 += u1; i2 += u2; }
        }
        if (lane == 63) { wred[wid] = i1; wred[4 + wid] = i2; }
    }
    __syncthreads();
    if (act) {
        float off1 = 0.f, off2 = 0.f;
        for (int w = 0; w < wid; ++w) { off1 += wred[w]; off2 += wred[4 + w]; }
        const float T1 = wred[0] + wred[1] + wred[2] + wred[3];
        const float T2 = wred[4] + wred[5] + wred[6] + wred[7];
        float pre1 = off1 + i1 - S1;
        float pre2 = off2 + i2 - S2;
        z1suf[2 * t] = T1 - pre1;
        z1suf[2 * t + 1] = T1 - pre1 - e1_0;
        z2pre[2 * t] = pre2;
        z2pre[2 * t + 1] = pre2 + e2_0;
        if (t == 0) { z1suf[512] = 0.f; z2pre[512] = T2; }
    }
    __syncthreads();

    if (act) {
        for (int rr = 0; rr < 2; ++rr) {
            int i = t + rr * 256;
            float d = dreg[rr];
            int lo = 0, hi = 512;
            while (lo < hi) {
                int mid = (lo + hi) >> 1;
                if (d + sA[mid] >= 0.f) hi = mid; else lo = mid + 1;
            }
            int k = lo;
            float g = d + M;
            float G = (g >= 0.f) ? g : 0.2f * g;
            float al = __expf(g - G);
            float be = __expf(0.2f * g - G);
            float Z = al * z1suf[k] + be * z2pre[k];
            float inv = 1.0f / Z;
            g_abk[bh * 512 + i] = make_float4(al * inv, be * inv,
                                              __int_as_float(k), 0.f);
        }
    }
}

// ---------------------------------------------------------------------------
// Kernel B2: attn_agg_fin v11 (R32) — float4 LDS tables + float2 hT reads
// (channel-pair interleaved) + fused pooling + optional x store.
// grid = 2048 blocks, 256 thr (4 waves = 4 heads).
// ---------------------------------------------------------------------------
__global__ __launch_bounds__(256) void attn_agg_fin(const float* __restrict__ hT,
                                                    const float4* __restrict__ g_rE,
                                                    const float4* __restrict__ g_abk,
                                                    const float* __restrict__ bias,
                                                    float* __restrict__ x,
                                                    float* __restrict__ pooled,
                                                    int storex) {
    // R27 bijective swizzle: id%8 = b%8.
    const int r8 = blockIdx.x & 7;
    const int qq = blockIdx.x >> 3;
    const int cg = qq & 31;                // 0..31
    const int b  = ((qq >> 5) << 3) | r8;  // 0..63
    const int c0 = cg * 2;
    const int t = threadIdx.x;
    const int lane = t & 63, wv = t >> 6;  // wv = head 0..3

    __shared__ float4 A12[4][512];         // {A1c0, A2c0, A1c1, A2c1}
    __shared__ float tots[4][2];
    __shared__ float sredP[4][2];

    {
        const int bh = b * 4 + wv;
        const int base = bh * 512;
        // R32: channel-pair stream — one float2 per node j.
        const float* hTb = hT + (size_t)(wv * 32 + cg) * 65536 + (size_t)(b * 512) * 2;
#pragma unroll
        for (int it = 0; it < 8; ++it) {
            int j = it * 64 + lane;
            float4 rE = g_rE[base + j];          // packed (rank, E1, E2)
            int rk = __float_as_int(rE.x);
            float2 hv = *(const float2*)&hTb[j * 2];   // {h[c0][j], h[c0+1][j]}
            int pk = ((rk & 7) << 6) | (rk >> 3);
            A12[wv][pk] = make_float4(rE.y * hv.x, rE.z * hv.x,
                                      rE.y * hv.y, rE.z * hv.y);   // one b128
        }
        // scan: all four planes in one pass (per-plane op order = R30)
        float a1c0[8], a2c0[8], a1c1[8], a2c1[8];
#pragma unroll
        for (int i = 0; i < 8; ++i) {
            float4 vv = A12[wv][i * 64 + lane];                // one b128
            a1c0[i] = vv.x; a2c0[i] = vv.y; a1c1[i] = vv.z; a2c1[i] = vv.w;
        }
        float s10 = 0.f, s20 = 0.f, s11 = 0.f, s21 = 0.f;
#pragma unroll
        for (int i = 0; i < 8; ++i) {
            s10 += a1c0[i]; s20 += a2c0[i]; s11 += a1c1[i]; s21 += a2c1[i];
        }
        float suf0 = s10, suf1 = s11;
#pragma unroll
        for (int off = 1; off < 64; off <<= 1) {
            float u0 = __shfl_down(suf0, off, 64);
            float u1 = __shfl_down(suf1, off, 64);
            if (lane + off < 64) { suf0 += u0; suf1 += u1; }
        }
        float run0 = suf0 - s10, run1 = suf1 - s11;      // exclusive suffix
        float pre0 = s20, pre1 = s21;
#pragma unroll
        for (int off = 1; off < 64; off <<= 1) {
            float u0 = __shfl_up(pre0, off, 64);
            float u1 = __shfl_up(pre1, off, 64);
            if (lane >= off) { pre0 += u0; pre1 += u1; }
        }
        float run20 = pre0 - s20, run21 = pre1 - s21;    // exclusive prefix
        if (lane == 63) { tots[wv][0] = pre0; tots[wv][1] = pre1; }
#pragma unroll
        for (int i = 7; i >= 0; --i) {
            run0 += a1c0[i]; a1c0[i] = run0;             // incl suffix
            run1 += a1c1[i]; a1c1[i] = run1;
        }
#pragma unroll
        for (int i = 0; i < 8; ++i) {
            float tv0 = a2c0[i]; a2c0[i] = run20; run20 += tv0;  // excl prefix
            float tv1 = a2c1[i]; a2c1[i] = run21; run21 += tv1;
        }
#pragma unroll
        for (int i = 0; i < 8; ++i)
            A12[wv][i * 64 + lane] = make_float4(a1c0[i], a2c0[i],
                                                 a1c1[i], a2c1[i]);  // one b128
    }
    __syncthreads();

    const float bv0 = bias[c0], bv1 = bias[c0 + 1];
    float p0 = 0.f, p1 = 0.f;              // per-thread pooled partials
#pragma unroll
    for (int rr = 0; rr < 2; ++rr) {
        const int i = t + rr * 256;
        float a0 = 0.f, a1 = 0.f;
#pragma unroll
        for (int head = 0; head < 4; ++head) {
            const int base = (b * 4 + head) * 512;
            float4 abk = g_abk[base + i];        // packed (aZ, bZ, k)
            int k = __float_as_int(abk.z);
            if (k < 512) {
                int pk = ((k & 7) << 6) | (k >> 3);
                float4 vv = A12[head][pk];       // one random b128
                a0 += abk.x * vv.x + abk.y * vv.y;
                a1 += abk.x * vv.z + abk.y * vv.w;
            } else {
                a0 += abk.y * tots[head][0];
                a1 += abk.y * tots[head][1];
            }
        }
        float2 o = make_float2(fmaxf(0.25f * a0 + bv0, 0.f),
                               fmaxf(0.25f * a1 + bv1, 0.f));
        if (storex) *(float2*)&x[(size_t)(b * 512 + i) * 64 + c0] = o;
        p0 += o.x; p1 += o.y;
    }

    // Fused pooling: this block exclusively owns (b, c0..c0+1) over all n.
#pragma unroll
    for (int m = 1; m <= 32; m <<= 1) {
        p0 += __shfl_xor(p0, m, 64);
        p1 += __shfl_xor(p1, m, 64);
    }
    if (lane == 0) { sredP[wv][0] = p0; sredP[wv][1] = p1; }
    __syncthreads();
    if (t == 0) {
        pooled[b * 64 + c0]     = sredP[0][0] + sredP[1][0] + sredP[2][0] + sredP[3][0];
        pooled[b * 64 + c0 + 1] = sredP[0][1] + sredP[1][1] + sredP[2][1] + sredP[3][1];
    }
}

// ---------------------------------------------------------------------------
// Kernel D: readout v2 — consumes 16KB pooled sums. grid 64 x 64 threads.
// ---------------------------------------------------------------------------
__global__ __launch_bounds__(64) void readout_kernel(const float* __restrict__ pooled,
                                                     const float* __restrict__ rw,
                                                     const float* __restrict__ rb,
                                                     float* __restrict__ out) {
    __shared__ float pl[64];
    int b = blockIdx.x, t = threadIdx.x;
    pl[t] = pooled[b * 64 + t] * (1.0f / 512.0f);
    __syncthreads();
    float a = rb[t];
    for (int cc = 0; cc < 64; ++cc) a += pl[cc] * rw[t * 64 + cc];
    out[b * 64 + t] = a;
}

extern "C" void kernel_launch(void* const* d_in, const int* in_sizes, int n_in,
                              void* d_out, int out_size, void* d_ws, size_t ws_size,
                              hipStream_t stream) {
    const float* emb       = (const float*)d_in[0];
    const float* lin_w     = (const float*)d_in[1];
    const float* att_src   = (const float*)d_in[2];
    const float* att_dst   = (const float*)d_in[3];
    const float* conv_b    = (const float*)d_in[4];
    const float* readout_w = (const float*)d_in[5];
    const float* readout_b = (const float*)d_in[6];
    float* out = (float*)d_out;

    float* ws   = (float*)d_ws;
    float* xbuf = ws;                    // 8 MB
    float* hT   = ws + 2097152;          // 32 MB, channel-pair interleaved (R32)
    float* meta = ws + 10485760;         // 4 MB

    float4* g_rE   = (float4*)meta;                // [256*512] (rank,E1,E2,-)
    float4* g_abk  = (float4*)(meta + 524288);     // [256*512] (aZ,bZ,k,-)
    float*  pooled = ws + 11534336;                // [64*64] over-n sums

    for (int l = 0; l < 3; ++l) {
        const float* xin = (l == 0) ? emb : xbuf;
        linprep_kernel<<<256, 512, 0, stream>>>(xin, lin_w + (size_t)l * 16384,
                                                att_src + l * 256, att_dst + l * 256,
                                                hT, g_rE, g_abk);
        attn_agg_fin<<<2048, 256, 0, stream>>>(hT, g_rE, g_abk,
                                               conv_b + l * 64, xbuf, pooled,
                                               (l < 2) ? 1 : 0);
    }
    readout_kernel<<<64, 64, 0, stream>>>(pooled, readout_w, readout_b, out);
}